// Round 14
// baseline (151.412 us; speedup 1.0000x reference)
//
#include <hip/hip_runtime.h>
#include <math.h>

#define BATCH 8
#define NN 2048
#define DIN 256
#define RANK 64
#define TOPKK 32
#define CANDMAX 96

static constexpr size_t A_ELEMS = (size_t)BATCH * NN * NN;   // 33554432
static constexpr size_t S_OFF   = A_ELEMS;
static constexpr size_t R_OFF   = 2 * A_ELEMS;
static constexpr size_t NROWS   = (size_t)BATCH * NN;        // 16384

// ws layout (float offsets) — every word rewritten before read, every launch
static constexpr size_t T_OFF      = 0;                      // T[16384][64]
static constexpr size_t STAT_OFF   = 1048576;                // {sum,sumsq}[16384][32]
static constexpr size_t STATUS_OFF = STAT_OFF + NROWS * 64;  // int[16384]
// total ≈ 8.5 MB

#define NEG_INF (-__builtin_inff())

// ---------------- threefry2x32, JAX partitionable counter-mode (verified r3) ----------------
__device__ __forceinline__ unsigned rotl32(unsigned x, int d) {
  return (x << d) | (x >> (32 - d));
}

__device__ unsigned threefry_bits(unsigned flat) {
  const unsigned ks0 = 0u, ks1 = 42u, ks2 = 0u ^ 42u ^ 0x1BD11BDAu;
  unsigned x0 = 0u + ks0;
  unsigned x1 = flat + ks1;
#define TF_ROUND(r) { x0 += x1; x1 = rotl32(x1, r); x1 ^= x0; }
  TF_ROUND(13) TF_ROUND(15) TF_ROUND(26) TF_ROUND(6)
  x0 += ks1; x1 += ks2 + 1u;
  TF_ROUND(17) TF_ROUND(29) TF_ROUND(16) TF_ROUND(24)
  x0 += ks2; x1 += ks0 + 2u;
  TF_ROUND(13) TF_ROUND(15) TF_ROUND(26) TF_ROUND(6)
  x0 += ks0; x1 += ks1 + 3u;
  TF_ROUND(17) TF_ROUND(29) TF_ROUND(16) TF_ROUND(24)
  x0 += ks1; x1 += ks2 + 4u;
  TF_ROUND(13) TF_ROUND(15) TF_ROUND(26) TF_ROUND(6)
  x0 += ks2; x1 += ks0 + 5u;
#undef TF_ROUND
  return x0 ^ x1;
}

__device__ __forceinline__ unsigned long long make_key(float v, int col) {
  unsigned u = __float_as_uint(v);
  u = (u & 0x80000000u) ? ~u : (u | 0x80000000u);
  return ((unsigned long long)u << 32) | (unsigned)(~col);
}

__device__ __forceinline__ void decode_key(unsigned long long key, float& val, int& col) {
  unsigned hi = (unsigned)(key >> 32);
  unsigned ub = (hi & 0x80000000u) ? (hi ^ 0x80000000u) : ~hi;
  val = __uint_as_float(ub);
  col = (int)(~(unsigned)key) & (NN - 1);
}

// lane MUST be the within-wave lane id (threadIdx.x & 63) (r5 bug)
__device__ __forceinline__ void bitonic64_desc(unsigned long long& key, int lane) {
#pragma unroll
  for (int k = 2; k <= 64; k <<= 1) {
#pragma unroll
    for (int j = k >> 1; j >= 1; j >>= 1) {
      unsigned long long o = __shfl_xor(key, j, 64);
      bool lower = (lane & j) == 0;
      bool desc  = (lane & k) == 0;
      bool takeMax = (lower == desc);
      bool kgo = key > o;
      key = (takeMax == kgo) ? key : o;
    }
  }
}

// softmax + dropout + renorm + SCATTER-ONLY A write (A pre-zeroed by s_stat)
__device__ __forceinline__ void epilogue_write(float* __restrict__ out,
                                               unsigned long long key,
                                               int g, int lane) {
  float val; int col;
  decode_key(key, val, col);
  float m = __shfl(val, 0, 64);
  float e = (lane < TOPKK) ? expf(val - m) : 0.f;
  float s1 = e;
#pragma unroll
  for (int off = 1; off < 64; off <<= 1) s1 += __shfl_xor(s1, off, 64);
  float a1 = e / fmaxf(s1, 1e-6f);

  float a2 = 0.f;
  if (lane < TOPKK) {
    unsigned flat = (unsigned)g * 2048u + (unsigned)col;
    unsigned bits = threefry_bits(flat);
    float u = __uint_as_float((bits >> 9) | 0x3f800000u) - 1.0f;
    if (u <= 0.9f) a2 = a1 * (1.f / 0.9f);
  }
  float s2 = a2;
#pragma unroll
  for (int off = 1; off < 64; off <<= 1) s2 += __shfl_xor(s2, off, 64);
  float av = a2 / fmaxf(s2, 1e-6f);

  if (lane < TOPKK) out[(size_t)g * NN + col] = av;
}

// ---------------- kernel 1: R = X*W -> out; T = (R*B)/8 -> ws (verified r4/r8) ----------------
__global__ __launch_bounds__(256) void rt_kernel(const float* __restrict__ X,
                                                 const float* __restrict__ W,
                                                 const float* __restrict__ Bm,
                                                 float* __restrict__ out,
                                                 float* __restrict__ ws) {
  __shared__ float Xs[32][256];
  __shared__ float Bs[64][64];
  __shared__ float Rs[32][64];
  const int t = threadIdx.x;
  const int blk = blockIdx.x;
  const int b  = blk >> 6;
  const int rb = blk & 63;
  const float* Xb = X + ((size_t)b * NN + (size_t)rb * 32) * DIN;

#pragma unroll
  for (int it = 0; it < 8; ++it) {
    int flat = it * 1024 + t * 4;
    *(float4*)&Xs[flat >> 8][flat & 255] = *(const float4*)(Xb + flat);
  }
#pragma unroll
  for (int it = 0; it < 4; ++it) {
    int flat = it * 1024 + t * 4;
    *(float4*)&Bs[flat >> 6][flat & 63] = *(const float4*)(Bm + flat);
  }
  __syncthreads();

  const int j = t & 63, rg = t >> 6;
  float acc[8] = {0.f, 0.f, 0.f, 0.f, 0.f, 0.f, 0.f, 0.f};
  for (int k = 0; k < DIN; k += 4) {
    float w0 = W[(k + 0) * RANK + j];
    float w1 = W[(k + 1) * RANK + j];
    float w2 = W[(k + 2) * RANK + j];
    float w3 = W[(k + 3) * RANK + j];
#pragma unroll
    for (int ii = 0; ii < 8; ++ii) {
      float4 xv = *(const float4*)&Xs[rg * 8 + ii][k];
      acc[ii] += xv.x * w0 + xv.y * w1 + xv.z * w2 + xv.w * w3;
    }
  }
  const size_t grow0 = (size_t)b * NN + (size_t)rb * 32;
  float* Rout = out + R_OFF + grow0 * RANK;
#pragma unroll
  for (int ii = 0; ii < 8; ++ii) {
    Rout[(size_t)(rg * 8 + ii) * RANK + j] = acc[ii];
    Rs[rg * 8 + ii][j] = acc[ii];
  }
  __syncthreads();

  float acc2[8] = {0.f, 0.f, 0.f, 0.f, 0.f, 0.f, 0.f, 0.f};
  for (int r = 0; r < RANK; r += 4) {
    float b0 = Bs[r + 0][j];
    float b1 = Bs[r + 1][j];
    float b2 = Bs[r + 2][j];
    float b3 = Bs[r + 3][j];
#pragma unroll
    for (int ii = 0; ii < 8; ++ii) {
      float4 rv = *(const float4*)&Rs[rg * 8 + ii][r];
      acc2[ii] += rv.x * b0 + rv.y * b1 + rv.z * b2 + rv.w * b3;
    }
  }
  float* Tout = ws + T_OFF + grow0 * RANK;
#pragma unroll
  for (int ii = 0; ii < 8; ++ii)
    Tout[(size_t)(rg * 8 + ii) * RANK + j] = acc2[ii] * 0.125f;
}

// ---------------- kernel 2: S = T * R^T + stat partials + A-zero; swizzled Rs + float4 S stores ----------------
__global__ __launch_bounds__(256) void s_stat_kernel(float* __restrict__ out,
                                                     float* __restrict__ ws) {
  __shared__ float Ts[64][68];   // row-major, padded (broadcast b128 reads)
  __shared__ float Rs[64][64];   // per row c: unit u stored at (u ^ (c>>2))
  const int t = threadIdx.x;
  const int bx = blockIdx.x;  // col tile
  const int by = blockIdx.y;  // row tile
  const int bz = blockIdx.z;  // batch
  const float* Tg = ws + T_OFF + ((size_t)bz * NN + (size_t)by * 64) * RANK;
  const float* Rg = out + R_OFF + ((size_t)bz * NN + (size_t)bx * 64) * RANK;

#pragma unroll
  for (int it = 0; it < 4; ++it) {
    int flat = it * 1024 + t * 4;
    int r = flat >> 6, c = flat & 63;
    *(float4*)&Ts[r][c] = *(const float4*)(Tg + flat);
    // Rs staged with unit swizzle: logical unit = c>>2, row = r
    int u_store = ((c >> 2) ^ (r >> 2)) & 15;
    *(float4*)&Rs[r][u_store * 4] = *(const float4*)(Rg + flat);
  }
  __syncthreads();

  const int tx = t & 15, ty = t >> 4;   // cols tx*4..tx*4+3 ; rows ty + 16*ii
  float acc[4][4];
#pragma unroll
  for (int ii = 0; ii < 4; ++ii)
#pragma unroll
    for (int jj = 0; jj < 4; ++jj) acc[ii][jj] = 0.f;

  for (int k = 0; k < 64; k += 4) {
    float4 a[4], bb[4];
#pragma unroll
    for (int ii = 0; ii < 4; ++ii) a[ii] = *(const float4*)&Ts[ty + 16 * ii][k];
#pragma unroll
    for (int jj = 0; jj < 4; ++jj) {
      int c = tx * 4 + jj;                  // c>>2 == tx
      bb[jj] = *(const float4*)&Rs[c][(((k >> 2) ^ tx) & 15) * 4];
    }
#pragma unroll
    for (int ii = 0; ii < 4; ++ii)
#pragma unroll
      for (int jj = 0; jj < 4; ++jj)
        acc[ii][jj] += a[ii].x * bb[jj].x + a[ii].y * bb[jj].y +
                       a[ii].z * bb[jj].z + a[ii].w * bb[jj].w;
  }

  float* Sb = out + S_OFF + (size_t)bz * NN * NN;
#pragma unroll
  for (int ii = 0; ii < 4; ++ii) {
    int n = by * 64 + ty + 16 * ii;
    float4 f = make_float4(acc[ii][0], acc[ii][1], acc[ii][2], acc[ii][3]);
    *(float4*)(Sb + (size_t)n * NN + bx * 64 + tx * 4) = f;
  }

  // zero this block's 64x64 A tile: 1024 float4 units = 4 iters x 256 threads
  {
    float* Ab = out + ((size_t)bz * NN + (size_t)by * 64) * NN + bx * 64;
    float4 z = make_float4(0.f, 0.f, 0.f, 0.f);
#pragma unroll
    for (int i = 0; i < 4; ++i) {
      int idx = i * 256 + t;       // [0, 1024)
      int r = idx >> 4;            // [0, 64)
      int c4 = idx & 15;           // [0, 16)
      *(float4*)(Ab + (size_t)r * NN + c4 * 4) = z;
    }
  }

  // per-row partial {sum, sumsq} over this block's 64 cols; 16-lane shuffle reduce
#pragma unroll
  for (int ii = 0; ii < 4; ++ii) {
    float sp = 0.f, ssp = 0.f;
#pragma unroll
    for (int jj = 0; jj < 4; ++jj) {
      sp += acc[ii][jj];
      ssp = fmaf(acc[ii][jj], acc[ii][jj], ssp);
    }
#pragma unroll
    for (int off = 1; off < 16; off <<= 1) {   // stays within the 16-lane tx group
      sp  += __shfl_xor(sp, off, 64);
      ssp += __shfl_xor(ssp, off, 64);
    }
    if (tx == 0) {
      int n = by * 64 + ty + 16 * ii;
      size_t g = (size_t)bz * NN + n;
      float2 st = make_float2(sp, ssp);
      *(float2*)&ws[STAT_OFF + (g * 32 + bx) * 2] = st;
    }
  }
}

// ---------------- kernel 3: topk: in-wave tau + ballot screen -> sort -> scatter epilogue ----------------
__global__ __launch_bounds__(256) void topk_kernel(float* __restrict__ out,
                                                   float* __restrict__ ws) {
  __shared__ unsigned long long cand[4][CANDMAX];  // 3 KB only
  const int t = threadIdx.x;
  const int wv = t >> 6, lane = t & 63;
  const int g = blockIdx.x * 4 + wv;
  const int n = g & (NN - 1);

  // in-wave tau: reduce this row's 32 stat partials (verified r10)
  float sp = 0.f, ssp = 0.f;
  if (lane < 32) {
    float2 p = *(const float2*)&ws[STAT_OFF + ((size_t)g * 32 + lane) * 2];
    sp = p.x; ssp = p.y;
  }
#pragma unroll
  for (int off = 1; off < 64; off <<= 1) {
    sp  += __shfl_xor(sp, off, 64);
    ssp += __shfl_xor(ssp, off, 64);
  }
  const float mu = sp * (1.f / 2048.f);
  const float sigma = sqrtf(fmaxf(ssp * (1.f / 2048.f) - mu * mu, 1e-12f));
  const float tau = mu + 1.8627f * sigma;          // target ~64 candidates

  const float* row = out + S_OFF + (size_t)g * NN;
  float v[32];
#pragma unroll
  for (int jj = 0; jj < 8; ++jj) {
    float4 f = *(const float4*)(row + jj * 256 + lane * 4);
    v[jj * 4 + 0] = f.x; v[jj * 4 + 1] = f.y;
    v[jj * 4 + 2] = f.z; v[jj * 4 + 3] = f.w;
  }

  // ---- ballot-prefix screen (no atomics); positions dense & unique (verified r10) ----
  const unsigned long long below = (1ull << lane) - 1ull;
  int base = 0;
#pragma unroll
  for (int jj = 0; jj < 32; ++jj) {
    int col = ((jj >> 2) << 8) + lane * 4 + (jj & 3);
    bool pred = (col != n) && (v[jj] > tau);
    unsigned long long mask = __ballot(pred);
    if (pred) {
      int pos = base + __popcll(mask & below);
      if (pos < CANDMAX) cand[wv][pos] = make_key(v[jj], col);
    }
    base += __popcll(mask);
  }
  const int c = base;                              // wave-uniform

  int* status = (int*)(ws + STATUS_OFF);
  if (c < TOPKK || c > CANDMAX) {                  // rare: defer to fallback kernel
    if (lane == 0) status[g] = 0;
    return;
  }
  if (lane == 0) status[g] = 1;

  __builtin_amdgcn_s_waitcnt(0);                   // LDS writes visible to own wave

  unsigned long long key;
  if (c <= 64) {
    key = (lane < c) ? cand[wv][lane] : 0ull;
    bitonic64_desc(key, lane);
  } else {
    key = cand[wv][lane];
    bitonic64_desc(key, lane);
    if (lane >= 32) { int idx = 64 + (lane - 32); key = (idx < c) ? cand[wv][idx] : 0ull; }
    bitonic64_desc(key, lane);
  }

  epilogue_write(out, key, g, lane);
}

// ---------------- kernel 4: fallback for rows with count outside [32,96] (expected ~1 row) ----------------
__global__ __launch_bounds__(256) void fb_kernel(float* __restrict__ out,
                                                 const float* __restrict__ ws) {
  __shared__ unsigned long long cand[4][64];
  const int t = threadIdx.x;
  const int wv = t >> 6, lane = t & 63;
  const int* status = (const int*)(ws + STATUS_OFF);

  for (int g = blockIdx.x * 4 + wv; g < (int)NROWS; g += 256 * 4) {
    if (status[g]) continue;
    const int n = g & (NN - 1);
    const float* row = out + S_OFF + (size_t)g * NN;
    float v[32];
#pragma unroll
    for (int jj = 0; jj < 8; ++jj) {
      float4 f = *(const float4*)(row + jj * 256 + lane * 4);
      v[jj * 4 + 0] = f.x; v[jj * 4 + 1] = f.y;
      v[jj * 4 + 2] = f.z; v[jj * 4 + 3] = f.w;
    }
    float s = 0.f, ss = 0.f;
#pragma unroll
    for (int jj = 0; jj < 32; ++jj) { s += v[jj]; ss = fmaf(v[jj], v[jj], ss); }
#pragma unroll
    for (int off = 1; off < 64; off <<= 1) {
      s += __shfl_xor(s, off, 64); ss += __shfl_xor(ss, off, 64);
    }
    const float mu = s * (1.f / 2048.f);
    const float sigma = sqrtf(fmaxf(ss * (1.f / 2048.f) - mu * mu, 1e-12f));
    {
      int d = n - lane * 4;
      if (d >= 0 && d < NN && (d & 255) < 4) v[((d >> 8) << 2) | (d & 3)] = NEG_INF;
    }
    float tau2 = mu + 2.0641f * sigma;
    float lo_b = -3.0e38f, hi_b = 3.0e38f;
    float step = sigma + 1e-20f;
    bool found = false;
    for (int it = 0; it < 40; ++it) {
      int cl = 0;
#pragma unroll
      for (int jj = 0; jj < 32; ++jj) cl += (v[jj] > tau2) ? 1 : 0;
#pragma unroll
      for (int off = 1; off < 64; off <<= 1) cl += __shfl_xor(cl, off, 64);
      if (cl >= TOPKK && cl <= 64) { found = true; break; }
      if (cl > 64) lo_b = fmaxf(lo_b, tau2); else hi_b = fminf(hi_b, tau2);
      float tn = 0.f; bool ok = false;
      if (it < 6) {
        float pp = fminf(fmaxf((float)cl, 1.f) * (1.f / 2048.f), 0.5f);
        float tt = sqrtf(-2.f * logf(pp));
        float zc = tt - (2.30753f + 0.27061f * tt) /
                        (1.f + tt * (0.99229f + 0.04481f * tt));
        zc = fmaxf(zc, 0.05f);
        tn = mu + 2.0641f * ((tau2 - mu) / zc);
        ok = (tn > lo_b && tn < hi_b);
      }
      if (!ok) {
        if (lo_b > -1.0e38f && hi_b < 1.0e38f) tn = 0.5f * lo_b + 0.5f * hi_b;
        else if (cl > 64) { tn = tau2 + step; step *= 2.f; }
        else              { tn = tau2 - step; step *= 2.f; }
      }
      tau2 = tn;
    }

    unsigned long long key = 0ull;
    if (found) {
      const unsigned long long below = (1ull << lane) - 1ull;
      int base = 0;
#pragma unroll
      for (int jj = 0; jj < 32; ++jj) {
        int col = ((jj >> 2) << 8) + lane * 4 + (jj & 3);
        bool pred = (v[jj] > tau2);
        unsigned long long mask = __ballot(pred);
        if (pred) cand[wv][base + __popcll(mask & below)] = make_key(v[jj], col);
        base += __popcll(mask);
      }
      __builtin_amdgcn_s_waitcnt(0);
      key = (lane < base) ? cand[wv][lane] : 0ull;
      bitonic64_desc(key, lane);
    } else {
      // exact serial extraction (measure-zero path)
      unsigned alive = 0xFFFFFFFFu;
      unsigned long long keysel = 0ull;
      for (int it = 0; it < TOPKK; ++it) {
        unsigned long long best = 0ull;
#pragma unroll
        for (int jj = 0; jj < 32; ++jj) {
          if ((alive >> jj) & 1u) {
            int col = ((jj >> 2) << 8) + lane * 4 + (jj & 3);
            unsigned long long kk = make_key(v[jj], col);
            if (kk > best) best = kk;
          }
        }
        unsigned long long b2 = best;
#pragma unroll
        for (int off = 1; off < 64; off <<= 1) {
          unsigned long long o = __shfl_xor(b2, off, 64);
          if (o > b2) b2 = o;
        }
        if (lane == it) keysel = b2;
        if (best == b2) {
#pragma unroll
          for (int jj = 0; jj < 32; ++jj) {
            int col = ((jj >> 2) << 8) + lane * 4 + (jj & 3);
            if (make_key(v[jj], col) == b2) alive &= ~(1u << jj);
          }
        }
      }
      key = keysel;
    }

    epilogue_write(out, key, g, lane);
  }
}

extern "C" void kernel_launch(void* const* d_in, const int* in_sizes, int n_in,
                              void* d_out, int out_size, void* d_ws, size_t ws_size,
                              hipStream_t stream) {
  const float* X  = (const float*)d_in[0];
  const float* W  = (const float*)d_in[1];
  const float* Bm = (const float*)d_in[2];
  float* out = (float*)d_out;
  float* ws  = (float*)d_ws;   // ~8.5 MB used

  hipLaunchKernelGGL(rt_kernel, dim3(512), dim3(256), 0, stream, X, W, Bm, out, ws);
  hipLaunchKernelGGL(s_stat_kernel, dim3(32, 32, 8), dim3(256), 0, stream, out, ws);
  hipLaunchKernelGGL(topk_kernel, dim3(4096), dim3(256), 0, stream, out, ws);
  hipLaunchKernelGGL(fb_kernel, dim3(256), dim3(256), 0, stream, out, ws);
}

// Round 15
// 145.979 us; speedup vs baseline: 1.0372x; 1.0372x over previous
//
#include <hip/hip_runtime.h>
#include <math.h>

#define BATCH 8
#define NN 2048
#define DIN 256
#define RANK 64
#define TOPKK 32
#define CANDMAX 96

static constexpr size_t A_ELEMS = (size_t)BATCH * NN * NN;   // 33554432
static constexpr size_t S_OFF   = A_ELEMS;
static constexpr size_t R_OFF   = 2 * A_ELEMS;
static constexpr size_t NROWS   = (size_t)BATCH * NN;        // 16384

// ws layout (float offsets) — every word rewritten before read, every launch
static constexpr size_t T_OFF      = 0;                      // T[16384][64]
static constexpr size_t STAT_OFF   = 1048576;                // {sum,sumsq}[16384][32]
static constexpr size_t STATUS_OFF = STAT_OFF + NROWS * 64;  // int[16384]
// total ≈ 8.5 MB

#define NEG_INF (-__builtin_inff())

// ---------------- threefry2x32, JAX partitionable counter-mode (verified r3) ----------------
__device__ __forceinline__ unsigned rotl32(unsigned x, int d) {
  return (x << d) | (x >> (32 - d));
}

__device__ unsigned threefry_bits(unsigned flat) {
  const unsigned ks0 = 0u, ks1 = 42u, ks2 = 0u ^ 42u ^ 0x1BD11BDAu;
  unsigned x0 = 0u + ks0;
  unsigned x1 = flat + ks1;
#define TF_ROUND(r) { x0 += x1; x1 = rotl32(x1, r); x1 ^= x0; }
  TF_ROUND(13) TF_ROUND(15) TF_ROUND(26) TF_ROUND(6)
  x0 += ks1; x1 += ks2 + 1u;
  TF_ROUND(17) TF_ROUND(29) TF_ROUND(16) TF_ROUND(24)
  x0 += ks2; x1 += ks0 + 2u;
  TF_ROUND(13) TF_ROUND(15) TF_ROUND(26) TF_ROUND(6)
  x0 += ks0; x1 += ks1 + 3u;
  TF_ROUND(17) TF_ROUND(29) TF_ROUND(16) TF_ROUND(24)
  x0 += ks1; x1 += ks2 + 4u;
  TF_ROUND(13) TF_ROUND(15) TF_ROUND(26) TF_ROUND(6)
  x0 += ks2; x1 += ks0 + 5u;
#undef TF_ROUND
  return x0 ^ x1;
}

__device__ __forceinline__ unsigned long long make_key(float v, int col) {
  unsigned u = __float_as_uint(v);
  u = (u & 0x80000000u) ? ~u : (u | 0x80000000u);
  return ((unsigned long long)u << 32) | (unsigned)(~col);
}

__device__ __forceinline__ void decode_key(unsigned long long key, float& val, int& col) {
  unsigned hi = (unsigned)(key >> 32);
  unsigned ub = (hi & 0x80000000u) ? (hi ^ 0x80000000u) : ~hi;
  val = __uint_as_float(ub);
  col = (int)(~(unsigned)key) & (NN - 1);
}

// lane MUST be the within-wave lane id (threadIdx.x & 63) (r5 bug)
__device__ __forceinline__ void bitonic64_desc(unsigned long long& key, int lane) {
#pragma unroll
  for (int k = 2; k <= 64; k <<= 1) {
#pragma unroll
    for (int j = k >> 1; j >= 1; j >>= 1) {
      unsigned long long o = __shfl_xor(key, j, 64);
      bool lower = (lane & j) == 0;
      bool desc  = (lane & k) == 0;
      bool takeMax = (lower == desc);
      bool kgo = key > o;
      key = (takeMax == kgo) ? key : o;
    }
  }
}

// softmax + dropout + renorm + SCATTER-ONLY A write (A pre-zeroed by rt_kernel)
__device__ __forceinline__ void epilogue_write(float* __restrict__ out,
                                               unsigned long long key,
                                               int g, int lane) {
  float val; int col;
  decode_key(key, val, col);
  float m = __shfl(val, 0, 64);
  float e = (lane < TOPKK) ? expf(val - m) : 0.f;
  float s1 = e;
#pragma unroll
  for (int off = 1; off < 64; off <<= 1) s1 += __shfl_xor(s1, off, 64);
  float a1 = e / fmaxf(s1, 1e-6f);

  float a2 = 0.f;
  if (lane < TOPKK) {
    unsigned flat = (unsigned)g * 2048u + (unsigned)col;
    unsigned bits = threefry_bits(flat);
    float u = __uint_as_float((bits >> 9) | 0x3f800000u) - 1.0f;
    if (u <= 0.9f) a2 = a1 * (1.f / 0.9f);
  }
  float s2 = a2;
#pragma unroll
  for (int off = 1; off < 64; off <<= 1) s2 += __shfl_xor(s2, off, 64);
  float av = a2 / fmaxf(s2, 1e-6f);

  if (lane < TOPKK) out[(size_t)g * NN + col] = av;
}

// ---------------- kernel 1: R = X*W -> out; T = (R*B)/8 -> ws; + grid-stride A-zero ----------------
__global__ __launch_bounds__(256) void rt_kernel(const float* __restrict__ X,
                                                 const float* __restrict__ W,
                                                 const float* __restrict__ Bm,
                                                 float* __restrict__ out,
                                                 float* __restrict__ ws) {
  __shared__ float Xs[32][256];
  __shared__ float Bs[64][64];
  __shared__ float Rs[32][64];
  const int t = threadIdx.x;
  const int blk = blockIdx.x;
  const int b  = blk >> 6;
  const int rb = blk & 63;
  const float* Xb = X + ((size_t)b * NN + (size_t)rb * 32) * DIN;

#pragma unroll
  for (int it = 0; it < 8; ++it) {
    int flat = it * 1024 + t * 4;
    *(float4*)&Xs[flat >> 8][flat & 255] = *(const float4*)(Xb + flat);
  }
#pragma unroll
  for (int it = 0; it < 4; ++it) {
    int flat = it * 1024 + t * 4;
    *(float4*)&Bs[flat >> 6][flat & 63] = *(const float4*)(Bm + flat);
  }
  __syncthreads();

  const int j = t & 63, rg = t >> 6;
  float acc[8] = {0.f, 0.f, 0.f, 0.f, 0.f, 0.f, 0.f, 0.f};
  for (int k = 0; k < DIN; k += 4) {
    float w0 = W[(k + 0) * RANK + j];
    float w1 = W[(k + 1) * RANK + j];
    float w2 = W[(k + 2) * RANK + j];
    float w3 = W[(k + 3) * RANK + j];
#pragma unroll
    for (int ii = 0; ii < 8; ++ii) {
      float4 xv = *(const float4*)&Xs[rg * 8 + ii][k];
      acc[ii] += xv.x * w0 + xv.y * w1 + xv.z * w2 + xv.w * w3;
    }
  }
  const size_t grow0 = (size_t)b * NN + (size_t)rb * 32;
  float* Rout = out + R_OFF + grow0 * RANK;
#pragma unroll
  for (int ii = 0; ii < 8; ++ii) {
    Rout[(size_t)(rg * 8 + ii) * RANK + j] = acc[ii];
    Rs[rg * 8 + ii][j] = acc[ii];
  }
  __syncthreads();

  float acc2[8] = {0.f, 0.f, 0.f, 0.f, 0.f, 0.f, 0.f, 0.f};
  for (int r = 0; r < RANK; r += 4) {
    float b0 = Bs[r + 0][j];
    float b1 = Bs[r + 1][j];
    float b2 = Bs[r + 2][j];
    float b3 = Bs[r + 3][j];
#pragma unroll
    for (int ii = 0; ii < 8; ++ii) {
      float4 rv = *(const float4*)&Rs[rg * 8 + ii][r];
      acc2[ii] += rv.x * b0 + rv.y * b1 + rv.z * b2 + rv.w * b3;
    }
  }
  float* Tout = ws + T_OFF + grow0 * RANK;
#pragma unroll
  for (int ii = 0; ii < 8; ++ii)
    Tout[(size_t)(rg * 8 + ii) * RANK + j] = acc2[ii] * 0.125f;

  // grid-stride zero of the whole A region (rt has idle BW; s_stat is BW-bound).
  // 8M float4 units / 512 blocks = 4096/block = 16/thread, fully coalesced.
  {
    float4* Az = (float4*)out;
    float4 z = make_float4(0.f, 0.f, 0.f, 0.f);
    size_t base = (size_t)blk * 4096 + t;
#pragma unroll
    for (int i = 0; i < 16; ++i)
      Az[base + (size_t)i * 256] = z;
  }
}

// ---------------- kernel 2: S = T * R^T + stat partials (swizzled Rs, float4 S stores) ----------------
__global__ __launch_bounds__(256) void s_stat_kernel(float* __restrict__ out,
                                                     float* __restrict__ ws) {
  __shared__ float Ts[64][68];   // row-major, padded (broadcast b128 reads)
  __shared__ float Rs[64][64];   // per row c: unit u stored at (u ^ (c>>2))
  const int t = threadIdx.x;
  const int bx = blockIdx.x;  // col tile
  const int by = blockIdx.y;  // row tile
  const int bz = blockIdx.z;  // batch
  const float* Tg = ws + T_OFF + ((size_t)bz * NN + (size_t)by * 64) * RANK;
  const float* Rg = out + R_OFF + ((size_t)bz * NN + (size_t)bx * 64) * RANK;

#pragma unroll
  for (int it = 0; it < 4; ++it) {
    int flat = it * 1024 + t * 4;
    int r = flat >> 6, c = flat & 63;
    *(float4*)&Ts[r][c] = *(const float4*)(Tg + flat);
    int u_store = ((c >> 2) ^ (r >> 2)) & 15;
    *(float4*)&Rs[r][u_store * 4] = *(const float4*)(Rg + flat);
  }
  __syncthreads();

  const int tx = t & 15, ty = t >> 4;   // cols tx*4..tx*4+3 ; rows ty + 16*ii
  float acc[4][4];
#pragma unroll
  for (int ii = 0; ii < 4; ++ii)
#pragma unroll
    for (int jj = 0; jj < 4; ++jj) acc[ii][jj] = 0.f;

  for (int k = 0; k < 64; k += 4) {
    float4 a[4], bb[4];
#pragma unroll
    for (int ii = 0; ii < 4; ++ii) a[ii] = *(const float4*)&Ts[ty + 16 * ii][k];
#pragma unroll
    for (int jj = 0; jj < 4; ++jj) {
      int c = tx * 4 + jj;                  // c>>2 == tx
      bb[jj] = *(const float4*)&Rs[c][(((k >> 2) ^ tx) & 15) * 4];
    }
#pragma unroll
    for (int ii = 0; ii < 4; ++ii)
#pragma unroll
      for (int jj = 0; jj < 4; ++jj)
        acc[ii][jj] += a[ii].x * bb[jj].x + a[ii].y * bb[jj].y +
                       a[ii].z * bb[jj].z + a[ii].w * bb[jj].w;
  }

  float* Sb = out + S_OFF + (size_t)bz * NN * NN;
#pragma unroll
  for (int ii = 0; ii < 4; ++ii) {
    int n = by * 64 + ty + 16 * ii;
    float4 f = make_float4(acc[ii][0], acc[ii][1], acc[ii][2], acc[ii][3]);
    *(float4*)(Sb + (size_t)n * NN + bx * 64 + tx * 4) = f;
  }

  // per-row partial {sum, sumsq} over this block's 64 cols; 16-lane shuffle reduce
#pragma unroll
  for (int ii = 0; ii < 4; ++ii) {
    float sp = 0.f, ssp = 0.f;
#pragma unroll
    for (int jj = 0; jj < 4; ++jj) {
      sp += acc[ii][jj];
      ssp = fmaf(acc[ii][jj], acc[ii][jj], ssp);
    }
#pragma unroll
    for (int off = 1; off < 16; off <<= 1) {   // stays within the 16-lane tx group
      sp  += __shfl_xor(sp, off, 64);
      ssp += __shfl_xor(ssp, off, 64);
    }
    if (tx == 0) {
      int n = by * 64 + ty + 16 * ii;
      size_t g = (size_t)bz * NN + n;
      float2 st = make_float2(sp, ssp);
      *(float2*)&ws[STAT_OFF + (g * 32 + bx) * 2] = st;
    }
  }
}

// ---------------- kernel 3: topk: in-wave tau + ballot screen -> sort -> scatter epilogue ----------------
__global__ __launch_bounds__(256) void topk_kernel(float* __restrict__ out,
                                                   float* __restrict__ ws) {
  __shared__ unsigned long long cand[4][CANDMAX];  // 3 KB only
  const int t = threadIdx.x;
  const int wv = t >> 6, lane = t & 63;
  const int g = blockIdx.x * 4 + wv;
  const int n = g & (NN - 1);

  // in-wave tau: reduce this row's 32 stat partials (verified r10)
  float sp = 0.f, ssp = 0.f;
  if (lane < 32) {
    float2 p = *(const float2*)&ws[STAT_OFF + ((size_t)g * 32 + lane) * 2];
    sp = p.x; ssp = p.y;
  }
#pragma unroll
  for (int off = 1; off < 64; off <<= 1) {
    sp  += __shfl_xor(sp, off, 64);
    ssp += __shfl_xor(ssp, off, 64);
  }
  const float mu = sp * (1.f / 2048.f);
  const float sigma = sqrtf(fmaxf(ssp * (1.f / 2048.f) - mu * mu, 1e-12f));
  const float tau = mu + 1.8627f * sigma;          // target ~64 candidates

  const float* row = out + S_OFF + (size_t)g * NN;
  float v[32];
#pragma unroll
  for (int jj = 0; jj < 8; ++jj) {
    float4 f = *(const float4*)(row + jj * 256 + lane * 4);
    v[jj * 4 + 0] = f.x; v[jj * 4 + 1] = f.y;
    v[jj * 4 + 2] = f.z; v[jj * 4 + 3] = f.w;
  }

  // ---- ballot-prefix screen (no atomics); positions dense & unique (verified r10) ----
  const unsigned long long below = (1ull << lane) - 1ull;
  int base = 0;
#pragma unroll
  for (int jj = 0; jj < 32; ++jj) {
    int col = ((jj >> 2) << 8) + lane * 4 + (jj & 3);
    bool pred = (col != n) && (v[jj] > tau);
    unsigned long long mask = __ballot(pred);
    if (pred) {
      int pos = base + __popcll(mask & below);
      if (pos < CANDMAX) cand[wv][pos] = make_key(v[jj], col);
    }
    base += __popcll(mask);
  }
  const int c = base;                              // wave-uniform

  int* status = (int*)(ws + STATUS_OFF);
  if (c < TOPKK || c > CANDMAX) {                  // rare: defer to fallback kernel
    if (lane == 0) status[g] = 0;
    return;
  }
  if (lane == 0) status[g] = 1;

  __builtin_amdgcn_s_waitcnt(0);                   // LDS writes visible to own wave

  unsigned long long key;
  if (c <= 64) {
    key = (lane < c) ? cand[wv][lane] : 0ull;
    bitonic64_desc(key, lane);
  } else {
    key = cand[wv][lane];
    bitonic64_desc(key, lane);
    if (lane >= 32) { int idx = 64 + (lane - 32); key = (idx < c) ? cand[wv][idx] : 0ull; }
    bitonic64_desc(key, lane);
  }

  epilogue_write(out, key, g, lane);
}

// ---------------- kernel 4: fallback for rows with count outside [32,96] (expected ~1 row) ----------------
__global__ __launch_bounds__(256) void fb_kernel(float* __restrict__ out,
                                                 const float* __restrict__ ws) {
  __shared__ unsigned long long cand[4][64];
  const int t = threadIdx.x;
  const int wv = t >> 6, lane = t & 63;
  const int* status = (const int*)(ws + STATUS_OFF);

  for (int g = blockIdx.x * 4 + wv; g < (int)NROWS; g += 256 * 4) {
    if (status[g]) continue;
    const int n = g & (NN - 1);
    const float* row = out + S_OFF + (size_t)g * NN;
    float v[32];
#pragma unroll
    for (int jj = 0; jj < 8; ++jj) {
      float4 f = *(const float4*)(row + jj * 256 + lane * 4);
      v[jj * 4 + 0] = f.x; v[jj * 4 + 1] = f.y;
      v[jj * 4 + 2] = f.z; v[jj * 4 + 3] = f.w;
    }
    float s = 0.f, ss = 0.f;
#pragma unroll
    for (int jj = 0; jj < 32; ++jj) { s += v[jj]; ss = fmaf(v[jj], v[jj], ss); }
#pragma unroll
    for (int off = 1; off < 64; off <<= 1) {
      s += __shfl_xor(s, off, 64); ss += __shfl_xor(ss, off, 64);
    }
    const float mu = s * (1.f / 2048.f);
    const float sigma = sqrtf(fmaxf(ss * (1.f / 2048.f) - mu * mu, 1e-12f));
    {
      int d = n - lane * 4;
      if (d >= 0 && d < NN && (d & 255) < 4) v[((d >> 8) << 2) | (d & 3)] = NEG_INF;
    }
    float tau2 = mu + 2.0641f * sigma;
    float lo_b = -3.0e38f, hi_b = 3.0e38f;
    float step = sigma + 1e-20f;
    bool found = false;
    for (int it = 0; it < 40; ++it) {
      int cl = 0;
#pragma unroll
      for (int jj = 0; jj < 32; ++jj) cl += (v[jj] > tau2) ? 1 : 0;
#pragma unroll
      for (int off = 1; off < 64; off <<= 1) cl += __shfl_xor(cl, off, 64);
      if (cl >= TOPKK && cl <= 64) { found = true; break; }
      if (cl > 64) lo_b = fmaxf(lo_b, tau2); else hi_b = fminf(hi_b, tau2);
      float tn = 0.f; bool ok = false;
      if (it < 6) {
        float pp = fminf(fmaxf((float)cl, 1.f) * (1.f / 2048.f), 0.5f);
        float tt = sqrtf(-2.f * logf(pp));
        float zc = tt - (2.30753f + 0.27061f * tt) /
                        (1.f + tt * (0.99229f + 0.04481f * tt));
        zc = fmaxf(zc, 0.05f);
        tn = mu + 2.0641f * ((tau2 - mu) / zc);
        ok = (tn > lo_b && tn < hi_b);
      }
      if (!ok) {
        if (lo_b > -1.0e38f && hi_b < 1.0e38f) tn = 0.5f * lo_b + 0.5f * hi_b;
        else if (cl > 64) { tn = tau2 + step; step *= 2.f; }
        else              { tn = tau2 - step; step *= 2.f; }
      }
      tau2 = tn;
    }

    unsigned long long key = 0ull;
    if (found) {
      const unsigned long long below = (1ull << lane) - 1ull;
      int base = 0;
#pragma unroll
      for (int jj = 0; jj < 32; ++jj) {
        int col = ((jj >> 2) << 8) + lane * 4 + (jj & 3);
        bool pred = (v[jj] > tau2);
        unsigned long long mask = __ballot(pred);
        if (pred) cand[wv][base + __popcll(mask & below)] = make_key(v[jj], col);
        base += __popcll(mask);
      }
      __builtin_amdgcn_s_waitcnt(0);
      key = (lane < base) ? cand[wv][lane] : 0ull;
      bitonic64_desc(key, lane);
    } else {
      // exact serial extraction (measure-zero path)
      unsigned alive = 0xFFFFFFFFu;
      unsigned long long keysel = 0ull;
      for (int it = 0; it < TOPKK; ++it) {
        unsigned long long best = 0ull;
#pragma unroll
        for (int jj = 0; jj < 32; ++jj) {
          if ((alive >> jj) & 1u) {
            int col = ((jj >> 2) << 8) + lane * 4 + (jj & 3);
            unsigned long long kk = make_key(v[jj], col);
            if (kk > best) best = kk;
          }
        }
        unsigned long long b2 = best;
#pragma unroll
        for (int off = 1; off < 64; off <<= 1) {
          unsigned long long o = __shfl_xor(b2, off, 64);
          if (o > b2) b2 = o;
        }
        if (lane == it) keysel = b2;
        if (best == b2) {
#pragma unroll
          for (int jj = 0; jj < 32; ++jj) {
            int col = ((jj >> 2) << 8) + lane * 4 + (jj & 3);
            if (make_key(v[jj], col) == b2) alive &= ~(1u << jj);
          }
        }
      }
      key = keysel;
    }

    epilogue_write(out, key, g, lane);
  }
}

extern "C" void kernel_launch(void* const* d_in, const int* in_sizes, int n_in,
                              void* d_out, int out_size, void* d_ws, size_t ws_size,
                              hipStream_t stream) {
  const float* X  = (const float*)d_in[0];
  const float* W  = (const float*)d_in[1];
  const float* Bm = (const float*)d_in[2];
  float* out = (float*)d_out;
  float* ws  = (float*)d_ws;   // ~8.5 MB used

  hipLaunchKernelGGL(rt_kernel, dim3(512), dim3(256), 0, stream, X, W, Bm, out, ws);
  hipLaunchKernelGGL(s_stat_kernel, dim3(32, 32, 8), dim3(256), 0, stream, out, ws);
  hipLaunchKernelGGL(topk_kernel, dim3(4096), dim3(256), 0, stream, out, ws);
  hipLaunchKernelGGL(fb_kernel, dim3(256), dim3(256), 0, stream, out, ws);
}

// Round 16
// 140.436 us; speedup vs baseline: 1.0782x; 1.0395x over previous
//
#include <hip/hip_runtime.h>
#include <math.h>

#define BATCH 8
#define NN 2048
#define DIN 256
#define RANK 64
#define TOPKK 32
#define CANDMAX 96

static constexpr size_t A_ELEMS = (size_t)BATCH * NN * NN;   // 33554432
static constexpr size_t S_OFF   = A_ELEMS;
static constexpr size_t R_OFF   = 2 * A_ELEMS;
static constexpr size_t NROWS   = (size_t)BATCH * NN;        // 16384

// ws layout (float offsets) — every word rewritten before read, every launch
static constexpr size_t T_OFF      = 0;                      // T[16384][64]
static constexpr size_t STAT_OFF   = 1048576;                // {sum,sumsq}[16384][32]
static constexpr size_t STATUS_OFF = STAT_OFF + NROWS * 64;  // int[16384]
// total ≈ 8.5 MB

#define NEG_INF (-__builtin_inff())

// ---------------- threefry2x32, JAX partitionable counter-mode (verified r3) ----------------
__device__ __forceinline__ unsigned rotl32(unsigned x, int d) {
  return (x << d) | (x >> (32 - d));
}

__device__ unsigned threefry_bits(unsigned flat) {
  const unsigned ks0 = 0u, ks1 = 42u, ks2 = 0u ^ 42u ^ 0x1BD11BDAu;
  unsigned x0 = 0u + ks0;
  unsigned x1 = flat + ks1;
#define TF_ROUND(r) { x0 += x1; x1 = rotl32(x1, r); x1 ^= x0; }
  TF_ROUND(13) TF_ROUND(15) TF_ROUND(26) TF_ROUND(6)
  x0 += ks1; x1 += ks2 + 1u;
  TF_ROUND(17) TF_ROUND(29) TF_ROUND(16) TF_ROUND(24)
  x0 += ks2; x1 += ks0 + 2u;
  TF_ROUND(13) TF_ROUND(15) TF_ROUND(26) TF_ROUND(6)
  x0 += ks0; x1 += ks1 + 3u;
  TF_ROUND(17) TF_ROUND(29) TF_ROUND(16) TF_ROUND(24)
  x0 += ks1; x1 += ks2 + 4u;
  TF_ROUND(13) TF_ROUND(15) TF_ROUND(26) TF_ROUND(6)
  x0 += ks2; x1 += ks0 + 5u;
#undef TF_ROUND
  return x0 ^ x1;
}

__device__ __forceinline__ unsigned long long make_key(float v, int col) {
  unsigned u = __float_as_uint(v);
  u = (u & 0x80000000u) ? ~u : (u | 0x80000000u);
  return ((unsigned long long)u << 32) | (unsigned)(~col);
}

__device__ __forceinline__ void decode_key(unsigned long long key, float& val, int& col) {
  unsigned hi = (unsigned)(key >> 32);
  unsigned ub = (hi & 0x80000000u) ? (hi ^ 0x80000000u) : ~hi;
  val = __uint_as_float(ub);
  col = (int)(~(unsigned)key) & (NN - 1);
}

// lane MUST be the within-wave lane id (threadIdx.x & 63) (r5 bug)
__device__ __forceinline__ void bitonic64_desc(unsigned long long& key, int lane) {
#pragma unroll
  for (int k = 2; k <= 64; k <<= 1) {
#pragma unroll
    for (int j = k >> 1; j >= 1; j >>= 1) {
      unsigned long long o = __shfl_xor(key, j, 64);
      bool lower = (lane & j) == 0;
      bool desc  = (lane & k) == 0;
      bool takeMax = (lower == desc);
      bool kgo = key > o;
      key = (takeMax == kgo) ? key : o;
    }
  }
}

// softmax + dropout + renorm + SCATTER-ONLY A write (A pre-zeroed by rt_kernel)
__device__ __forceinline__ void epilogue_write(float* __restrict__ out,
                                               unsigned long long key,
                                               int g, int lane) {
  float val; int col;
  decode_key(key, val, col);
  float m = __shfl(val, 0, 64);
  float e = (lane < TOPKK) ? expf(val - m) : 0.f;
  float s1 = e;
#pragma unroll
  for (int off = 1; off < 64; off <<= 1) s1 += __shfl_xor(s1, off, 64);
  float a1 = e / fmaxf(s1, 1e-6f);

  float a2 = 0.f;
  if (lane < TOPKK) {
    unsigned flat = (unsigned)g * 2048u + (unsigned)col;
    unsigned bits = threefry_bits(flat);
    float u = __uint_as_float((bits >> 9) | 0x3f800000u) - 1.0f;
    if (u <= 0.9f) a2 = a1 * (1.f / 0.9f);
  }
  float s2 = a2;
#pragma unroll
  for (int off = 1; off < 64; off <<= 1) s2 += __shfl_xor(s2, off, 64);
  float av = a2 / fmaxf(s2, 1e-6f);

  if (lane < TOPKK) out[(size_t)g * NN + col] = av;
}

// ---------------- kernel 1: R = X*W -> out; T = (R*B)/8 -> ws; + grid-stride A-zero ----------------
__global__ __launch_bounds__(256) void rt_kernel(const float* __restrict__ X,
                                                 const float* __restrict__ W,
                                                 const float* __restrict__ Bm,
                                                 float* __restrict__ out,
                                                 float* __restrict__ ws) {
  __shared__ float Xs[32][256];
  __shared__ float Bs[64][64];
  __shared__ float Rs[32][64];
  const int t = threadIdx.x;
  const int blk = blockIdx.x;
  const int b  = blk >> 6;
  const int rb = blk & 63;
  const float* Xb = X + ((size_t)b * NN + (size_t)rb * 32) * DIN;

#pragma unroll
  for (int it = 0; it < 8; ++it) {
    int flat = it * 1024 + t * 4;
    *(float4*)&Xs[flat >> 8][flat & 255] = *(const float4*)(Xb + flat);
  }
#pragma unroll
  for (int it = 0; it < 4; ++it) {
    int flat = it * 1024 + t * 4;
    *(float4*)&Bs[flat >> 6][flat & 63] = *(const float4*)(Bm + flat);
  }
  __syncthreads();

  const int j = t & 63, rg = t >> 6;
  float acc[8] = {0.f, 0.f, 0.f, 0.f, 0.f, 0.f, 0.f, 0.f};
  for (int k = 0; k < DIN; k += 4) {
    float w0 = W[(k + 0) * RANK + j];
    float w1 = W[(k + 1) * RANK + j];
    float w2 = W[(k + 2) * RANK + j];
    float w3 = W[(k + 3) * RANK + j];
#pragma unroll
    for (int ii = 0; ii < 8; ++ii) {
      float4 xv = *(const float4*)&Xs[rg * 8 + ii][k];
      acc[ii] += xv.x * w0 + xv.y * w1 + xv.z * w2 + xv.w * w3;
    }
  }
  const size_t grow0 = (size_t)b * NN + (size_t)rb * 32;
  float* Rout = out + R_OFF + grow0 * RANK;
#pragma unroll
  for (int ii = 0; ii < 8; ++ii) {
    Rout[(size_t)(rg * 8 + ii) * RANK + j] = acc[ii];
    Rs[rg * 8 + ii][j] = acc[ii];
  }
  __syncthreads();

  float acc2[8] = {0.f, 0.f, 0.f, 0.f, 0.f, 0.f, 0.f, 0.f};
  for (int r = 0; r < RANK; r += 4) {
    float b0 = Bs[r + 0][j];
    float b1 = Bs[r + 1][j];
    float b2 = Bs[r + 2][j];
    float b3 = Bs[r + 3][j];
#pragma unroll
    for (int ii = 0; ii < 8; ++ii) {
      float4 rv = *(const float4*)&Rs[rg * 8 + ii][r];
      acc2[ii] += rv.x * b0 + rv.y * b1 + rv.z * b2 + rv.w * b3;
    }
  }
  float* Tout = ws + T_OFF + grow0 * RANK;
#pragma unroll
  for (int ii = 0; ii < 8; ++ii)
    Tout[(size_t)(rg * 8 + ii) * RANK + j] = acc2[ii] * 0.125f;

  // grid-stride zero of the whole A region (rt has idle BW; s_stat is BW-bound).
  {
    float4* Az = (float4*)out;
    float4 z = make_float4(0.f, 0.f, 0.f, 0.f);
    size_t base = (size_t)blk * 4096 + t;
#pragma unroll
    for (int i = 0; i < 16; ++i)
      Az[base + (size_t)i * 256] = z;
  }
}

// ---------------- kernel 2: S = T * R^T + stat partials; 8x4 thread tile (128x64 block) ----------------
__global__ __launch_bounds__(256) void s_stat_kernel(float* __restrict__ out,
                                                     float* __restrict__ ws) {
  __shared__ float Ts[128][68];  // row-major, padded (broadcast b128 reads), 34 KB
  __shared__ float Rs[64][64];   // per row c: unit u stored at (u ^ (c>>2)), 16 KB
  const int t = threadIdx.x;
  const int bx = blockIdx.x;  // col tile (64 cols)
  const int by = blockIdx.y;  // row tile (128 rows)
  const int bz = blockIdx.z;  // batch
  const float* Tg = ws + T_OFF + ((size_t)bz * NN + (size_t)by * 128) * RANK;
  const float* Rg = out + R_OFF + ((size_t)bz * NN + (size_t)bx * 64) * RANK;

#pragma unroll
  for (int it = 0; it < 8; ++it) {
    int flat = it * 1024 + t * 4;
    int r = flat >> 6, c = flat & 63;
    *(float4*)&Ts[r][c] = *(const float4*)(Tg + flat);
  }
#pragma unroll
  for (int it = 0; it < 4; ++it) {
    int flat = it * 1024 + t * 4;
    int r = flat >> 6, c = flat & 63;
    int u_store = ((c >> 2) ^ (r >> 2)) & 15;
    *(float4*)&Rs[r][u_store * 4] = *(const float4*)(Rg + flat);
  }
  __syncthreads();

  const int tx = t & 15, ty = t >> 4;   // cols tx*4..+3 ; rows ty + 16*ii, ii<8
  float acc[8][4];
#pragma unroll
  for (int ii = 0; ii < 8; ++ii)
#pragma unroll
    for (int jj = 0; jj < 4; ++jj) acc[ii][jj] = 0.f;

  for (int k = 0; k < 64; k += 4) {
    float4 a[8], bb[4];
#pragma unroll
    for (int ii = 0; ii < 8; ++ii) a[ii] = *(const float4*)&Ts[ty + 16 * ii][k];
#pragma unroll
    for (int jj = 0; jj < 4; ++jj) {
      int c = tx * 4 + jj;                  // c>>2 == tx
      bb[jj] = *(const float4*)&Rs[c][(((k >> 2) ^ tx) & 15) * 4];
    }
#pragma unroll
    for (int ii = 0; ii < 8; ++ii)
#pragma unroll
      for (int jj = 0; jj < 4; ++jj)
        acc[ii][jj] += a[ii].x * bb[jj].x + a[ii].y * bb[jj].y +
                       a[ii].z * bb[jj].z + a[ii].w * bb[jj].w;
  }

  float* Sb = out + S_OFF + (size_t)bz * NN * NN;
#pragma unroll
  for (int ii = 0; ii < 8; ++ii) {
    int n = by * 128 + ty + 16 * ii;
    float4 f = make_float4(acc[ii][0], acc[ii][1], acc[ii][2], acc[ii][3]);
    *(float4*)(Sb + (size_t)n * NN + bx * 64 + tx * 4) = f;
  }

  // per-row partial {sum, sumsq} over this block's 64 cols; 16-lane shuffle reduce
#pragma unroll
  for (int ii = 0; ii < 8; ++ii) {
    float sp = 0.f, ssp = 0.f;
#pragma unroll
    for (int jj = 0; jj < 4; ++jj) {
      sp += acc[ii][jj];
      ssp = fmaf(acc[ii][jj], acc[ii][jj], ssp);
    }
#pragma unroll
    for (int off = 1; off < 16; off <<= 1) {   // stays within the 16-lane tx group
      sp  += __shfl_xor(sp, off, 64);
      ssp += __shfl_xor(ssp, off, 64);
    }
    if (tx == 0) {
      int n = by * 128 + ty + 16 * ii;
      size_t g = (size_t)bz * NN + n;
      float2 st = make_float2(sp, ssp);
      *(float2*)&ws[STAT_OFF + (g * 32 + bx) * 2] = st;
    }
  }
}

// ---------------- kernel 3: topk: in-wave tau + prefix screen -> sort -> scatter epilogue ----------------
__global__ __launch_bounds__(256) void topk_kernel(float* __restrict__ out,
                                                   float* __restrict__ ws) {
  __shared__ unsigned long long cand[4][CANDMAX];  // 3 KB only
  const int t = threadIdx.x;
  const int wv = t >> 6, lane = t & 63;
  const int g = blockIdx.x * 4 + wv;
  const int n = g & (NN - 1);

  // in-wave tau: reduce this row's 32 stat partials (verified r10)
  float sp = 0.f, ssp = 0.f;
  if (lane < 32) {
    float2 p = *(const float2*)&ws[STAT_OFF + ((size_t)g * 32 + lane) * 2];
    sp = p.x; ssp = p.y;
  }
#pragma unroll
  for (int off = 1; off < 64; off <<= 1) {
    sp  += __shfl_xor(sp, off, 64);
    ssp += __shfl_xor(ssp, off, 64);
  }
  const float mu = sp * (1.f / 2048.f);
  const float sigma = sqrtf(fmaxf(ssp * (1.f / 2048.f) - mu * mu, 1e-12f));
  const float tau = mu + 1.8627f * sigma;          // target ~64 candidates

  const float* row = out + S_OFF + (size_t)g * NN;
  float v[32];
#pragma unroll
  for (int jj = 0; jj < 8; ++jj) {
    float4 f = *(const float4*)(row + jj * 256 + lane * 4);
    v[jj * 4 + 0] = f.x; v[jj * 4 + 1] = f.y;
    v[jj * 4 + 2] = f.z; v[jj * 4 + 3] = f.w;
  }

  // ---- prefix screen (single shuffle-prefix; order-free, sort is total) ----
  unsigned pmask = 0u;
  int mycnt = 0;
#pragma unroll
  for (int jj = 0; jj < 32; ++jj) {
    int col = ((jj >> 2) << 8) + lane * 4 + (jj & 3);
    if (col != n && v[jj] > tau) { pmask |= 1u << jj; ++mycnt; }
  }
  int pre = mycnt;
#pragma unroll
  for (int off = 1; off < 64; off <<= 1) {
    int o = __shfl_up(pre, off, 64);
    if (lane >= off) pre += o;
  }
  const int base0 = pre - mycnt;                   // exclusive prefix
  const int c = __shfl(pre, 63, 64);               // wave-uniform total

  int* status = (int*)(ws + STATUS_OFF);
  if (c < TOPKK || c > CANDMAX) {                  // rare: defer to fallback kernel
    if (lane == 0) status[g] = 0;
    return;
  }
  if (lane == 0) status[g] = 1;

  {
    int pos = base0;
#pragma unroll
    for (int jj = 0; jj < 32; ++jj) {
      if ((pmask >> jj) & 1u) {
        int col = ((jj >> 2) << 8) + lane * 4 + (jj & 3);
        cand[wv][pos] = make_key(v[jj], col);
        ++pos;
      }
    }
  }
  __builtin_amdgcn_s_waitcnt(0);                   // LDS writes visible to own wave

  unsigned long long key;
  if (c <= 64) {
    key = (lane < c) ? cand[wv][lane] : 0ull;
    bitonic64_desc(key, lane);
  } else {
    key = cand[wv][lane];
    bitonic64_desc(key, lane);
    if (lane >= 32) { int idx = 64 + (lane - 32); key = (idx < c) ? cand[wv][idx] : 0ull; }
    bitonic64_desc(key, lane);
  }

  epilogue_write(out, key, g, lane);
}

// ---------------- kernel 4: fallback for rows with count outside [32,96] (expected ~1 row) ----------------
__global__ __launch_bounds__(256) void fb_kernel(float* __restrict__ out,
                                                 const float* __restrict__ ws) {
  __shared__ unsigned long long cand[4][64];
  const int t = threadIdx.x;
  const int wv = t >> 6, lane = t & 63;
  const int* status = (const int*)(ws + STATUS_OFF);

  for (int g = blockIdx.x * 4 + wv; g < (int)NROWS; g += 256 * 4) {
    if (status[g]) continue;
    const int n = g & (NN - 1);
    const float* row = out + S_OFF + (size_t)g * NN;
    float v[32];
#pragma unroll
    for (int jj = 0; jj < 8; ++jj) {
      float4 f = *(const float4*)(row + jj * 256 + lane * 4);
      v[jj * 4 + 0] = f.x; v[jj * 4 + 1] = f.y;
      v[jj * 4 + 2] = f.z; v[jj * 4 + 3] = f.w;
    }
    float s = 0.f, ss = 0.f;
#pragma unroll
    for (int jj = 0; jj < 32; ++jj) { s += v[jj]; ss = fmaf(v[jj], v[jj], ss); }
#pragma unroll
    for (int off = 1; off < 64; off <<= 1) {
      s += __shfl_xor(s, off, 64); ss += __shfl_xor(ss, off, 64);
    }
    const float mu = s * (1.f / 2048.f);
    const float sigma = sqrtf(fmaxf(ss * (1.f / 2048.f) - mu * mu, 1e-12f));
    {
      int d = n - lane * 4;
      if (d >= 0 && d < NN && (d & 255) < 4) v[((d >> 8) << 2) | (d & 3)] = NEG_INF;
    }
    float tau2 = mu + 2.0641f * sigma;
    float lo_b = -3.0e38f, hi_b = 3.0e38f;
    float step = sigma + 1e-20f;
    bool found = false;
    for (int it = 0; it < 40; ++it) {
      int cl = 0;
#pragma unroll
      for (int jj = 0; jj < 32; ++jj) cl += (v[jj] > tau2) ? 1 : 0;
#pragma unroll
      for (int off = 1; off < 64; off <<= 1) cl += __shfl_xor(cl, off, 64);
      if (cl >= TOPKK && cl <= 64) { found = true; break; }
      if (cl > 64) lo_b = fmaxf(lo_b, tau2); else hi_b = fminf(hi_b, tau2);
      float tn = 0.f; bool ok = false;
      if (it < 6) {
        float pp = fminf(fmaxf((float)cl, 1.f) * (1.f / 2048.f), 0.5f);
        float tt = sqrtf(-2.f * logf(pp));
        float zc = tt - (2.30753f + 0.27061f * tt) /
                        (1.f + tt * (0.99229f + 0.04481f * tt));
        zc = fmaxf(zc, 0.05f);
        tn = mu + 2.0641f * ((tau2 - mu) / zc);
        ok = (tn > lo_b && tn < hi_b);
      }
      if (!ok) {
        if (lo_b > -1.0e38f && hi_b < 1.0e38f) tn = 0.5f * lo_b + 0.5f * hi_b;
        else if (cl > 64) { tn = tau2 + step; step *= 2.f; }
        else              { tn = tau2 - step; step *= 2.f; }
      }
      tau2 = tn;
    }

    unsigned long long key = 0ull;
    if (found) {
      const unsigned long long below = (1ull << lane) - 1ull;
      int base = 0;
#pragma unroll
      for (int jj = 0; jj < 32; ++jj) {
        int col = ((jj >> 2) << 8) + lane * 4 + (jj & 3);
        bool pred = (v[jj] > tau2);
        unsigned long long mask = __ballot(pred);
        if (pred) cand[wv][base + __popcll(mask & below)] = make_key(v[jj], col);
        base += __popcll(mask);
      }
      __builtin_amdgcn_s_waitcnt(0);
      key = (lane < base) ? cand[wv][lane] : 0ull;
      bitonic64_desc(key, lane);
    } else {
      // exact serial extraction (measure-zero path)
      unsigned alive = 0xFFFFFFFFu;
      unsigned long long keysel = 0ull;
      for (int it = 0; it < TOPKK; ++it) {
        unsigned long long best = 0ull;
#pragma unroll
        for (int jj = 0; jj < 32; ++jj) {
          if ((alive >> jj) & 1u) {
            int col = ((jj >> 2) << 8) + lane * 4 + (jj & 3);
            unsigned long long kk = make_key(v[jj], col);
            if (kk > best) best = kk;
          }
        }
        unsigned long long b2 = best;
#pragma unroll
        for (int off = 1; off < 64; off <<= 1) {
          unsigned long long o = __shfl_xor(b2, off, 64);
          if (o > b2) b2 = o;
        }
        if (lane == it) keysel = b2;
        if (best == b2) {
#pragma unroll
          for (int jj = 0; jj < 32; ++jj) {
            int col = ((jj >> 2) << 8) + lane * 4 + (jj & 3);
            if (make_key(v[jj], col) == b2) alive &= ~(1u << jj);
          }
        }
      }
      key = keysel;
    }

    epilogue_write(out, key, g, lane);
  }
}

extern "C" void kernel_launch(void* const* d_in, const int* in_sizes, int n_in,
                              void* d_out, int out_size, void* d_ws, size_t ws_size,
                              hipStream_t stream) {
  const float* X  = (const float*)d_in[0];
  const float* W  = (const float*)d_in[1];
  const float* Bm = (const float*)d_in[2];
  float* out = (float*)d_out;
  float* ws  = (float*)d_ws;   // ~8.5 MB used

  hipLaunchKernelGGL(rt_kernel, dim3(512), dim3(256), 0, stream, X, W, Bm, out, ws);
  hipLaunchKernelGGL(s_stat_kernel, dim3(32, 16, 8), dim3(256), 0, stream, out, ws);
  hipLaunchKernelGGL(topk_kernel, dim3(4096), dim3(256), 0, stream, out, ws);
  hipLaunchKernelGGL(fb_kernel, dim3(256), dim3(256), 0, stream, out, ws);
}

// Round 17
// 135.186 us; speedup vs baseline: 1.1200x; 1.0388x over previous
//
#include <hip/hip_runtime.h>
#include <math.h>

#define BATCH 8
#define NN 2048
#define DIN 256
#define RANK 64
#define TOPKK 32
#define CANDMAX 96

static constexpr size_t A_ELEMS = (size_t)BATCH * NN * NN;   // 33554432
static constexpr size_t S_OFF   = A_ELEMS;
static constexpr size_t R_OFF   = 2 * A_ELEMS;
static constexpr size_t NROWS   = (size_t)BATCH * NN;        // 16384

// ws layout (float offsets) — every word rewritten before read, every launch
static constexpr size_t T_OFF      = 0;                      // T[16384][64]
static constexpr size_t STAT_OFF   = 1048576;                // {sum,sumsq}[16384][16]
static constexpr size_t STATUS_OFF = STAT_OFF + NROWS * 32;  // int[16384]
// total ≈ 6.3 MB

#define NEG_INF (-__builtin_inff())

// ---------------- threefry2x32, JAX partitionable counter-mode (verified r3) ----------------
__device__ __forceinline__ unsigned rotl32(unsigned x, int d) {
  return (x << d) | (x >> (32 - d));
}

__device__ unsigned threefry_bits(unsigned flat) {
  const unsigned ks0 = 0u, ks1 = 42u, ks2 = 0u ^ 42u ^ 0x1BD11BDAu;
  unsigned x0 = 0u + ks0;
  unsigned x1 = flat + ks1;
#define TF_ROUND(r) { x0 += x1; x1 = rotl32(x1, r); x1 ^= x0; }
  TF_ROUND(13) TF_ROUND(15) TF_ROUND(26) TF_ROUND(6)
  x0 += ks1; x1 += ks2 + 1u;
  TF_ROUND(17) TF_ROUND(29) TF_ROUND(16) TF_ROUND(24)
  x0 += ks2; x1 += ks0 + 2u;
  TF_ROUND(13) TF_ROUND(15) TF_ROUND(26) TF_ROUND(6)
  x0 += ks0; x1 += ks1 + 3u;
  TF_ROUND(17) TF_ROUND(29) TF_ROUND(16) TF_ROUND(24)
  x0 += ks1; x1 += ks2 + 4u;
  TF_ROUND(13) TF_ROUND(15) TF_ROUND(26) TF_ROUND(6)
  x0 += ks2; x1 += ks0 + 5u;
#undef TF_ROUND
  return x0 ^ x1;
}

__device__ __forceinline__ unsigned long long make_key(float v, int col) {
  unsigned u = __float_as_uint(v);
  u = (u & 0x80000000u) ? ~u : (u | 0x80000000u);
  return ((unsigned long long)u << 32) | (unsigned)(~col);
}

__device__ __forceinline__ void decode_key(unsigned long long key, float& val, int& col) {
  unsigned hi = (unsigned)(key >> 32);
  unsigned ub = (hi & 0x80000000u) ? (hi ^ 0x80000000u) : ~hi;
  val = __uint_as_float(ub);
  col = (int)(~(unsigned)key) & (NN - 1);
}

// lane MUST be the within-wave lane id (threadIdx.x & 63) (r5 bug)
__device__ __forceinline__ void bitonic64_desc(unsigned long long& key, int lane) {
#pragma unroll
  for (int k = 2; k <= 64; k <<= 1) {
#pragma unroll
    for (int j = k >> 1; j >= 1; j >>= 1) {
      unsigned long long o = __shfl_xor(key, j, 64);
      bool lower = (lane & j) == 0;
      bool desc  = (lane & k) == 0;
      bool takeMax = (lower == desc);
      bool kgo = key > o;
      key = (takeMax == kgo) ? key : o;
    }
  }
}

// softmax + dropout + renorm + SCATTER-ONLY A write (A pre-zeroed by rt_kernel)
__device__ __forceinline__ void epilogue_write(float* __restrict__ out,
                                               unsigned long long key,
                                               int g, int lane) {
  float val; int col;
  decode_key(key, val, col);
  float m = __shfl(val, 0, 64);
  float e = (lane < TOPKK) ? expf(val - m) : 0.f;
  float s1 = e;
#pragma unroll
  for (int off = 1; off < 64; off <<= 1) s1 += __shfl_xor(s1, off, 64);
  float a1 = e / fmaxf(s1, 1e-6f);

  float a2 = 0.f;
  if (lane < TOPKK) {
    unsigned flat = (unsigned)g * 2048u + (unsigned)col;
    unsigned bits = threefry_bits(flat);
    float u = __uint_as_float((bits >> 9) | 0x3f800000u) - 1.0f;
    if (u <= 0.9f) a2 = a1 * (1.f / 0.9f);
  }
  float s2 = a2;
#pragma unroll
  for (int off = 1; off < 64; off <<= 1) s2 += __shfl_xor(s2, off, 64);
  float av = a2 / fmaxf(s2, 1e-6f);

  if (lane < TOPKK) out[(size_t)g * NN + col] = av;
}

// ---------------- kernel 1: R = X*W -> out; T = (R*B)/8 -> ws; + grid-stride A-zero ----------------
__global__ __launch_bounds__(256) void rt_kernel(const float* __restrict__ X,
                                                 const float* __restrict__ W,
                                                 const float* __restrict__ Bm,
                                                 float* __restrict__ out,
                                                 float* __restrict__ ws) {
  __shared__ float Xs[32][256];
  __shared__ float Bs[64][64];
  __shared__ float Rs[32][64];
  const int t = threadIdx.x;
  const int blk = blockIdx.x;
  const int b  = blk >> 6;
  const int rb = blk & 63;
  const float* Xb = X + ((size_t)b * NN + (size_t)rb * 32) * DIN;

#pragma unroll
  for (int it = 0; it < 8; ++it) {
    int flat = it * 1024 + t * 4;
    *(float4*)&Xs[flat >> 8][flat & 255] = *(const float4*)(Xb + flat);
  }
#pragma unroll
  for (int it = 0; it < 4; ++it) {
    int flat = it * 1024 + t * 4;
    *(float4*)&Bs[flat >> 6][flat & 63] = *(const float4*)(Bm + flat);
  }
  __syncthreads();

  const int j = t & 63, rg = t >> 6;
  float acc[8] = {0.f, 0.f, 0.f, 0.f, 0.f, 0.f, 0.f, 0.f};
  for (int k = 0; k < DIN; k += 4) {
    float w0 = W[(k + 0) * RANK + j];
    float w1 = W[(k + 1) * RANK + j];
    float w2 = W[(k + 2) * RANK + j];
    float w3 = W[(k + 3) * RANK + j];
#pragma unroll
    for (int ii = 0; ii < 8; ++ii) {
      float4 xv = *(const float4*)&Xs[rg * 8 + ii][k];
      acc[ii] += xv.x * w0 + xv.y * w1 + xv.z * w2 + xv.w * w3;
    }
  }
  const size_t grow0 = (size_t)b * NN + (size_t)rb * 32;
  float* Rout = out + R_OFF + grow0 * RANK;
#pragma unroll
  for (int ii = 0; ii < 8; ++ii) {
    Rout[(size_t)(rg * 8 + ii) * RANK + j] = acc[ii];
    Rs[rg * 8 + ii][j] = acc[ii];
  }
  __syncthreads();

  float acc2[8] = {0.f, 0.f, 0.f, 0.f, 0.f, 0.f, 0.f, 0.f};
  for (int r = 0; r < RANK; r += 4) {
    float b0 = Bs[r + 0][j];
    float b1 = Bs[r + 1][j];
    float b2 = Bs[r + 2][j];
    float b3 = Bs[r + 3][j];
#pragma unroll
    for (int ii = 0; ii < 8; ++ii) {
      float4 rv = *(const float4*)&Rs[rg * 8 + ii][r];
      acc2[ii] += rv.x * b0 + rv.y * b1 + rv.z * b2 + rv.w * b3;
    }
  }
  float* Tout = ws + T_OFF + grow0 * RANK;
#pragma unroll
  for (int ii = 0; ii < 8; ++ii)
    Tout[(size_t)(rg * 8 + ii) * RANK + j] = acc2[ii] * 0.125f;

  // grid-stride zero of the whole A region (rt has idle BW; s_stat is LDS-bound).
  {
    float4* Az = (float4*)out;
    float4 z = make_float4(0.f, 0.f, 0.f, 0.f);
    size_t base = (size_t)blk * 4096 + t;
#pragma unroll
    for (int i = 0; i < 16; ++i)
      Az[base + (size_t)i * 256] = z;
  }
}

// ---------------- kernel 2: S = T * R^T + stat partials; 8x8 thread tile (128x128 block) ----------------
__global__ __launch_bounds__(256) void s_stat_kernel(float* __restrict__ out,
                                                     float* __restrict__ ws) {
  __shared__ float Ts[128][68];  // row-major, padded (broadcast b128 reads), 34.8 KB
  __shared__ float Rs[128][64];  // per row c: unit u stored at (u ^ (c>>2))&15, 32.8 KB
  const int t = threadIdx.x;
  const int bx = blockIdx.x;  // col tile (128 cols)
  const int by = blockIdx.y;  // row tile (128 rows)
  const int bz = blockIdx.z;  // batch
  const float* Tg = ws + T_OFF + ((size_t)bz * NN + (size_t)by * 128) * RANK;
  const float* Rg = out + R_OFF + ((size_t)bz * NN + (size_t)bx * 128) * RANK;

#pragma unroll
  for (int it = 0; it < 8; ++it) {
    int flat = it * 1024 + t * 4;
    int r = flat >> 6, c = flat & 63;
    *(float4*)&Ts[r][c] = *(const float4*)(Tg + flat);
    int u_store = ((c >> 2) ^ (r >> 2)) & 15;
    *(float4*)&Rs[r][u_store * 4] = *(const float4*)(Rg + flat);
  }
  __syncthreads();

  const int tx = t & 15, ty = t >> 4;   // rows ty + 16*ii (ii<8); cols jh*64 + tx*4 + jq
  float acc[8][8];
#pragma unroll
  for (int ii = 0; ii < 8; ++ii)
#pragma unroll
    for (int jj = 0; jj < 8; ++jj) acc[ii][jj] = 0.f;

  for (int k = 0; k < 64; k += 4) {
    float4 a[8], bb[8];
#pragma unroll
    for (int ii = 0; ii < 8; ++ii) a[ii] = *(const float4*)&Ts[ty + 16 * ii][k];
#pragma unroll
    for (int jj = 0; jj < 8; ++jj) {
      int c = (jj >> 2) * 64 + tx * 4 + (jj & 3);   // (c>>2)&15 == tx for both halves
      bb[jj] = *(const float4*)&Rs[c][(((k >> 2) ^ tx) & 15) * 4];
    }
#pragma unroll
    for (int ii = 0; ii < 8; ++ii)
#pragma unroll
      for (int jj = 0; jj < 8; ++jj)
        acc[ii][jj] += a[ii].x * bb[jj].x + a[ii].y * bb[jj].y +
                       a[ii].z * bb[jj].z + a[ii].w * bb[jj].w;
  }

  float* Sb = out + S_OFF + (size_t)bz * NN * NN;
#pragma unroll
  for (int ii = 0; ii < 8; ++ii) {
    int n = by * 128 + ty + 16 * ii;
    float4 f0 = make_float4(acc[ii][0], acc[ii][1], acc[ii][2], acc[ii][3]);
    float4 f1 = make_float4(acc[ii][4], acc[ii][5], acc[ii][6], acc[ii][7]);
    *(float4*)(Sb + (size_t)n * NN + bx * 128 + tx * 4) = f0;
    *(float4*)(Sb + (size_t)n * NN + bx * 128 + 64 + tx * 4) = f1;
  }

  // per-row partial {sum, sumsq} over this block's 128 cols; 16-lane shuffle reduce
#pragma unroll
  for (int ii = 0; ii < 8; ++ii) {
    float sp = 0.f, ssp = 0.f;
#pragma unroll
    for (int jj = 0; jj < 8; ++jj) {
      sp += acc[ii][jj];
      ssp = fmaf(acc[ii][jj], acc[ii][jj], ssp);
    }
#pragma unroll
    for (int off = 1; off < 16; off <<= 1) {   // stays within the 16-lane tx group
      sp  += __shfl_xor(sp, off, 64);
      ssp += __shfl_xor(ssp, off, 64);
    }
    if (tx == 0) {
      int n = by * 128 + ty + 16 * ii;
      size_t g = (size_t)bz * NN + n;
      float2 st = make_float2(sp, ssp);
      *(float2*)&ws[STAT_OFF + (g * 16 + bx) * 2] = st;
    }
  }
}

// ---------------- kernel 3: topk: in-wave tau + prefix screen -> sort -> scatter epilogue ----------------
__global__ __launch_bounds__(256) void topk_kernel(float* __restrict__ out,
                                                   float* __restrict__ ws) {
  __shared__ unsigned long long cand[4][CANDMAX];  // 3 KB only
  const int t = threadIdx.x;
  const int wv = t >> 6, lane = t & 63;
  const int g = blockIdx.x * 4 + wv;
  const int n = g & (NN - 1);

  // in-wave tau: reduce this row's 16 stat partials
  float sp = 0.f, ssp = 0.f;
  if (lane < 16) {
    float2 p = *(const float2*)&ws[STAT_OFF + ((size_t)g * 16 + lane) * 2];
    sp = p.x; ssp = p.y;
  }
#pragma unroll
  for (int off = 1; off < 64; off <<= 1) {
    sp  += __shfl_xor(sp, off, 64);
    ssp += __shfl_xor(ssp, off, 64);
  }
  const float mu = sp * (1.f / 2048.f);
  const float sigma = sqrtf(fmaxf(ssp * (1.f / 2048.f) - mu * mu, 1e-12f));
  const float tau = mu + 1.8627f * sigma;          // target ~64 candidates

  const float* row = out + S_OFF + (size_t)g * NN;
  float v[32];
#pragma unroll
  for (int jj = 0; jj < 8; ++jj) {
    float4 f = *(const float4*)(row + jj * 256 + lane * 4);
    v[jj * 4 + 0] = f.x; v[jj * 4 + 1] = f.y;
    v[jj * 4 + 2] = f.z; v[jj * 4 + 3] = f.w;
  }

  // ---- prefix screen (single shuffle-prefix; order-free, sort is total) ----
  unsigned pmask = 0u;
  int mycnt = 0;
#pragma unroll
  for (int jj = 0; jj < 32; ++jj) {
    int col = ((jj >> 2) << 8) + lane * 4 + (jj & 3);
    if (col != n && v[jj] > tau) { pmask |= 1u << jj; ++mycnt; }
  }
  int pre = mycnt;
#pragma unroll
  for (int off = 1; off < 64; off <<= 1) {
    int o = __shfl_up(pre, off, 64);
    if (lane >= off) pre += o;
  }
  const int base0 = pre - mycnt;                   // exclusive prefix
  const int c = __shfl(pre, 63, 64);               // wave-uniform total

  int* status = (int*)(ws + STATUS_OFF);
  if (c < TOPKK || c > CANDMAX) {                  // rare: defer to fallback kernel
    if (lane == 0) status[g] = 0;
    return;
  }
  if (lane == 0) status[g] = 1;

  {
    int pos = base0;
#pragma unroll
    for (int jj = 0; jj < 32; ++jj) {
      if ((pmask >> jj) & 1u) {
        int col = ((jj >> 2) << 8) + lane * 4 + (jj & 3);
        cand[wv][pos] = make_key(v[jj], col);
        ++pos;
      }
    }
  }
  __builtin_amdgcn_s_waitcnt(0);                   // LDS writes visible to own wave

  unsigned long long key;
  if (c <= 64) {
    key = (lane < c) ? cand[wv][lane] : 0ull;
    bitonic64_desc(key, lane);
  } else {
    key = cand[wv][lane];
    bitonic64_desc(key, lane);
    if (lane >= 32) { int idx = 64 + (lane - 32); key = (idx < c) ? cand[wv][idx] : 0ull; }
    bitonic64_desc(key, lane);
  }

  epilogue_write(out, key, g, lane);
}

// ---------------- kernel 4: fallback for rows with count outside [32,96] (expected ~1 row) ----------------
__global__ __launch_bounds__(256) void fb_kernel(float* __restrict__ out,
                                                 const float* __restrict__ ws) {
  __shared__ unsigned long long cand[4][64];
  const int t = threadIdx.x;
  const int wv = t >> 6, lane = t & 63;
  const int* status = (const int*)(ws + STATUS_OFF);

  for (int g = blockIdx.x * 4 + wv; g < (int)NROWS; g += 256 * 4) {
    if (status[g]) continue;
    const int n = g & (NN - 1);
    const float* row = out + S_OFF + (size_t)g * NN;
    float v[32];
#pragma unroll
    for (int jj = 0; jj < 8; ++jj) {
      float4 f = *(const float4*)(row + jj * 256 + lane * 4);
      v[jj * 4 + 0] = f.x; v[jj * 4 + 1] = f.y;
      v[jj * 4 + 2] = f.z; v[jj * 4 + 3] = f.w;
    }
    float s = 0.f, ss = 0.f;
#pragma unroll
    for (int jj = 0; jj < 32; ++jj) { s += v[jj]; ss = fmaf(v[jj], v[jj], ss); }
#pragma unroll
    for (int off = 1; off < 64; off <<= 1) {
      s += __shfl_xor(s, off, 64); ss += __shfl_xor(ss, off, 64);
    }
    const float mu = s * (1.f / 2048.f);
    const float sigma = sqrtf(fmaxf(ss * (1.f / 2048.f) - mu * mu, 1e-12f));
    {
      int d = n - lane * 4;
      if (d >= 0 && d < NN && (d & 255) < 4) v[((d >> 8) << 2) | (d & 3)] = NEG_INF;
    }
    float tau2 = mu + 2.0641f * sigma;
    float lo_b = -3.0e38f, hi_b = 3.0e38f;
    float step = sigma + 1e-20f;
    bool found = false;
    for (int it = 0; it < 40; ++it) {
      int cl = 0;
#pragma unroll
      for (int jj = 0; jj < 32; ++jj) cl += (v[jj] > tau2) ? 1 : 0;
#pragma unroll
      for (int off = 1; off < 64; off <<= 1) cl += __shfl_xor(cl, off, 64);
      if (cl >= TOPKK && cl <= 64) { found = true; break; }
      if (cl > 64) lo_b = fmaxf(lo_b, tau2); else hi_b = fminf(hi_b, tau2);
      float tn = 0.f; bool ok = false;
      if (it < 6) {
        float pp = fminf(fmaxf((float)cl, 1.f) * (1.f / 2048.f), 0.5f);
        float tt = sqrtf(-2.f * logf(pp));
        float zc = tt - (2.30753f + 0.27061f * tt) /
                        (1.f + tt * (0.99229f + 0.04481f * tt));
        zc = fmaxf(zc, 0.05f);
        tn = mu + 2.0641f * ((tau2 - mu) / zc);
        ok = (tn > lo_b && tn < hi_b);
      }
      if (!ok) {
        if (lo_b > -1.0e38f && hi_b < 1.0e38f) tn = 0.5f * lo_b + 0.5f * hi_b;
        else if (cl > 64) { tn = tau2 + step; step *= 2.f; }
        else              { tn = tau2 - step; step *= 2.f; }
      }
      tau2 = tn;
    }

    unsigned long long key = 0ull;
    if (found) {
      const unsigned long long below = (1ull << lane) - 1ull;
      int base = 0;
#pragma unroll
      for (int jj = 0; jj < 32; ++jj) {
        int col = ((jj >> 2) << 8) + lane * 4 + (jj & 3);
        bool pred = (v[jj] > tau2);
        unsigned long long mask = __ballot(pred);
        if (pred) cand[wv][base + __popcll(mask & below)] = make_key(v[jj], col);
        base += __popcll(mask);
      }
      __builtin_amdgcn_s_waitcnt(0);
      key = (lane < base) ? cand[wv][lane] : 0ull;
      bitonic64_desc(key, lane);
    } else {
      // exact serial extraction (measure-zero path)
      unsigned alive = 0xFFFFFFFFu;
      unsigned long long keysel = 0ull;
      for (int it = 0; it < TOPKK; ++it) {
        unsigned long long best = 0ull;
#pragma unroll
        for (int jj = 0; jj < 32; ++jj) {
          if ((alive >> jj) & 1u) {
            int col = ((jj >> 2) << 8) + lane * 4 + (jj & 3);
            unsigned long long kk = make_key(v[jj], col);
            if (kk > best) best = kk;
          }
        }
        unsigned long long b2 = best;
#pragma unroll
        for (int off = 1; off < 64; off <<= 1) {
          unsigned long long o = __shfl_xor(b2, off, 64);
          if (o > b2) b2 = o;
        }
        if (lane == it) keysel = b2;
        if (best == b2) {
#pragma unroll
          for (int jj = 0; jj < 32; ++jj) {
            int col = ((jj >> 2) << 8) + lane * 4 + (jj & 3);
            if (make_key(v[jj], col) == b2) alive &= ~(1u << jj);
          }
        }
      }
      key = keysel;
    }

    epilogue_write(out, key, g, lane);
  }
}

extern "C" void kernel_launch(void* const* d_in, const int* in_sizes, int n_in,
                              void* d_out, int out_size, void* d_ws, size_t ws_size,
                              hipStream_t stream) {
  const float* X  = (const float*)d_in[0];
  const float* W  = (const float*)d_in[1];
  const float* Bm = (const float*)d_in[2];
  float* out = (float*)d_out;
  float* ws  = (float*)d_ws;   // ~6.3 MB used

  hipLaunchKernelGGL(rt_kernel, dim3(512), dim3(256), 0, stream, X, W, Bm, out, ws);
  hipLaunchKernelGGL(s_stat_kernel, dim3(16, 16, 8), dim3(256), 0, stream, out, ws);
  hipLaunchKernelGGL(topk_kernel, dim3(4096), dim3(256), 0, stream, out, ws);
  hipLaunchKernelGGL(fb_kernel, dim3(256), dim3(256), 0, stream, out, ws);
}

// Round 19
// 133.377 us; speedup vs baseline: 1.1352x; 1.0136x over previous
//
#include <hip/hip_runtime.h>
#include <math.h>

#define BATCH 8
#define NN 2048
#define DIN 256
#define RANK 64
#define TOPKK 32
#define CANDMAX 96

typedef float v4f __attribute__((ext_vector_type(4)));

static constexpr size_t A_ELEMS = (size_t)BATCH * NN * NN;   // 33554432
static constexpr size_t S_OFF   = A_ELEMS;
static constexpr size_t R_OFF   = 2 * A_ELEMS;
static constexpr size_t NROWS   = (size_t)BATCH * NN;        // 16384

// ws layout (float offsets) — every word rewritten before read, every launch
static constexpr size_t T_OFF      = 0;                      // T[16384][64]
static constexpr size_t STAT_OFF   = 1048576;                // {sum,sumsq}[16384][16]
static constexpr size_t STATUS_OFF = STAT_OFF + NROWS * 32;  // int[16384]
// total ≈ 6.3 MB

#define NEG_INF (-__builtin_inff())

// ---------------- threefry2x32, JAX partitionable counter-mode (verified r3) ----------------
__device__ __forceinline__ unsigned rotl32(unsigned x, int d) {
  return (x << d) | (x >> (32 - d));
}

__device__ unsigned threefry_bits(unsigned flat) {
  const unsigned ks0 = 0u, ks1 = 42u, ks2 = 0u ^ 42u ^ 0x1BD11BDAu;
  unsigned x0 = 0u + ks0;
  unsigned x1 = flat + ks1;
#define TF_ROUND(r) { x0 += x1; x1 = rotl32(x1, r); x1 ^= x0; }
  TF_ROUND(13) TF_ROUND(15) TF_ROUND(26) TF_ROUND(6)
  x0 += ks1; x1 += ks2 + 1u;
  TF_ROUND(17) TF_ROUND(29) TF_ROUND(16) TF_ROUND(24)
  x0 += ks2; x1 += ks0 + 2u;
  TF_ROUND(13) TF_ROUND(15) TF_ROUND(26) TF_ROUND(6)
  x0 += ks0; x1 += ks1 + 3u;
  TF_ROUND(17) TF_ROUND(29) TF_ROUND(16) TF_ROUND(24)
  x0 += ks1; x1 += ks2 + 4u;
  TF_ROUND(13) TF_ROUND(15) TF_ROUND(26) TF_ROUND(6)
  x0 += ks2; x1 += ks0 + 5u;
#undef TF_ROUND
  return x0 ^ x1;
}

__device__ __forceinline__ unsigned long long make_key(float v, int col) {
  unsigned u = __float_as_uint(v);
  u = (u & 0x80000000u) ? ~u : (u | 0x80000000u);
  return ((unsigned long long)u << 32) | (unsigned)(~col);
}

__device__ __forceinline__ void decode_key(unsigned long long key, float& val, int& col) {
  unsigned hi = (unsigned)(key >> 32);
  unsigned ub = (hi & 0x80000000u) ? (hi ^ 0x80000000u) : ~hi;
  val = __uint_as_float(ub);
  col = (int)(~(unsigned)key) & (NN - 1);
}

// lane MUST be the within-wave lane id (threadIdx.x & 63) (r5 bug)
__device__ __forceinline__ void bitonic64_desc(unsigned long long& key, int lane) {
#pragma unroll
  for (int k = 2; k <= 64; k <<= 1) {
#pragma unroll
    for (int j = k >> 1; j >= 1; j >>= 1) {
      unsigned long long o = __shfl_xor(key, j, 64);
      bool lower = (lane & j) == 0;
      bool desc  = (lane & k) == 0;
      bool takeMax = (lower == desc);
      bool kgo = key > o;
      key = (takeMax == kgo) ? key : o;
    }
  }
}

// softmax + dropout + renorm + SCATTER-ONLY A write (A pre-zeroed by rt_kernel)
__device__ __forceinline__ void epilogue_write(float* __restrict__ out,
                                               unsigned long long key,
                                               int g, int lane) {
  float val; int col;
  decode_key(key, val, col);
  float m = __shfl(val, 0, 64);
  float e = (lane < TOPKK) ? expf(val - m) : 0.f;
  float s1 = e;
#pragma unroll
  for (int off = 1; off < 64; off <<= 1) s1 += __shfl_xor(s1, off, 64);
  float a1 = e / fmaxf(s1, 1e-6f);

  float a2 = 0.f;
  if (lane < TOPKK) {
    unsigned flat = (unsigned)g * 2048u + (unsigned)col;
    unsigned bits = threefry_bits(flat);
    float u = __uint_as_float((bits >> 9) | 0x3f800000u) - 1.0f;
    if (u <= 0.9f) a2 = a1 * (1.f / 0.9f);
  }
  float s2 = a2;
#pragma unroll
  for (int off = 1; off < 64; off <<= 1) s2 += __shfl_xor(s2, off, 64);
  float av = a2 / fmaxf(s2, 1e-6f);

  if (lane < TOPKK) out[(size_t)g * NN + col] = av;
}

// ---------------- kernel 1: R = X*W -> out; T = (R*B)/8 -> ws; + grid-stride A-zero (nt) ----------------
__global__ __launch_bounds__(256) void rt_kernel(const float* __restrict__ X,
                                                 const float* __restrict__ W,
                                                 const float* __restrict__ Bm,
                                                 float* __restrict__ out,
                                                 float* __restrict__ ws) {
  __shared__ float Xs[32][256];
  __shared__ float Bs[64][64];
  __shared__ float Rs[32][64];
  const int t = threadIdx.x;
  const int blk = blockIdx.x;
  const int b  = blk >> 6;
  const int rb = blk & 63;
  const float* Xb = X + ((size_t)b * NN + (size_t)rb * 32) * DIN;

#pragma unroll
  for (int it = 0; it < 8; ++it) {
    int flat = it * 1024 + t * 4;
    *(float4*)&Xs[flat >> 8][flat & 255] = *(const float4*)(Xb + flat);
  }
#pragma unroll
  for (int it = 0; it < 4; ++it) {
    int flat = it * 1024 + t * 4;
    *(float4*)&Bs[flat >> 6][flat & 63] = *(const float4*)(Bm + flat);
  }
  __syncthreads();

  const int j = t & 63, rg = t >> 6;
  float acc[8] = {0.f, 0.f, 0.f, 0.f, 0.f, 0.f, 0.f, 0.f};
  for (int k = 0; k < DIN; k += 4) {
    float w0 = W[(k + 0) * RANK + j];
    float w1 = W[(k + 1) * RANK + j];
    float w2 = W[(k + 2) * RANK + j];
    float w3 = W[(k + 3) * RANK + j];
#pragma unroll
    for (int ii = 0; ii < 8; ++ii) {
      float4 xv = *(const float4*)&Xs[rg * 8 + ii][k];
      acc[ii] += xv.x * w0 + xv.y * w1 + xv.z * w2 + xv.w * w3;
    }
  }
  const size_t grow0 = (size_t)b * NN + (size_t)rb * 32;
  float* Rout = out + R_OFF + grow0 * RANK;
#pragma unroll
  for (int ii = 0; ii < 8; ++ii) {
    Rout[(size_t)(rg * 8 + ii) * RANK + j] = acc[ii];
    Rs[rg * 8 + ii][j] = acc[ii];
  }
  __syncthreads();

  float acc2[8] = {0.f, 0.f, 0.f, 0.f, 0.f, 0.f, 0.f, 0.f};
  for (int r = 0; r < RANK; r += 4) {
    float b0 = Bs[r + 0][j];
    float b1 = Bs[r + 1][j];
    float b2 = Bs[r + 2][j];
    float b3 = Bs[r + 3][j];
#pragma unroll
    for (int ii = 0; ii < 8; ++ii) {
      float4 rv = *(const float4*)&Rs[rg * 8 + ii][r];
      acc2[ii] += rv.x * b0 + rv.y * b1 + rv.z * b2 + rv.w * b3;
    }
  }
  float* Tout = ws + T_OFF + grow0 * RANK;
#pragma unroll
  for (int ii = 0; ii < 8; ++ii)
    Tout[(size_t)(rg * 8 + ii) * RANK + j] = acc2[ii] * 0.125f;

  // grid-stride zero of the whole A region — NON-TEMPORAL so the zeros don't
  // evict S from L3 (S must stay resident for topk's re-read).
  {
    v4f* Az = (v4f*)out;
    v4f z = {0.f, 0.f, 0.f, 0.f};
    size_t base = (size_t)blk * 4096 + t;
#pragma unroll
    for (int i = 0; i < 16; ++i)
      __builtin_nontemporal_store(z, Az + base + (size_t)i * 256);
  }
}

// ---------------- kernel 2: S = T * R^T + stat partials; 8x8 thread tile (128x128 block) ----------------
__global__ __launch_bounds__(256) void s_stat_kernel(float* __restrict__ out,
                                                     float* __restrict__ ws) {
  __shared__ float Ts[128][68];  // row-major, padded (broadcast b128 reads), 34.8 KB
  __shared__ float Rs[128][64];  // per row c: unit u stored at (u ^ (c>>2))&15, 32.8 KB
  const int t = threadIdx.x;
  const int bx = blockIdx.x;  // col tile (128 cols)
  const int by = blockIdx.y;  // row tile (128 rows)
  const int bz = blockIdx.z;  // batch
  const float* Tg = ws + T_OFF + ((size_t)bz * NN + (size_t)by * 128) * RANK;
  const float* Rg = out + R_OFF + ((size_t)bz * NN + (size_t)bx * 128) * RANK;

#pragma unroll
  for (int it = 0; it < 8; ++it) {
    int flat = it * 1024 + t * 4;
    int r = flat >> 6, c = flat & 63;
    *(float4*)&Ts[r][c] = *(const float4*)(Tg + flat);
    int u_store = ((c >> 2) ^ (r >> 2)) & 15;
    *(float4*)&Rs[r][u_store * 4] = *(const float4*)(Rg + flat);
  }
  __syncthreads();

  const int tx = t & 15, ty = t >> 4;   // rows ty + 16*ii (ii<8); cols jh*64 + tx*4 + jq
  float acc[8][8];
#pragma unroll
  for (int ii = 0; ii < 8; ++ii)
#pragma unroll
    for (int jj = 0; jj < 8; ++jj) acc[ii][jj] = 0.f;

  for (int k = 0; k < 64; k += 4) {
    float4 a[8], bb[8];
#pragma unroll
    for (int ii = 0; ii < 8; ++ii) a[ii] = *(const float4*)&Ts[ty + 16 * ii][k];
#pragma unroll
    for (int jj = 0; jj < 8; ++jj) {
      int c = (jj >> 2) * 64 + tx * 4 + (jj & 3);   // (c>>2)&15 == tx for both halves
      bb[jj] = *(const float4*)&Rs[c][(((k >> 2) ^ tx) & 15) * 4];
    }
#pragma unroll
    for (int ii = 0; ii < 8; ++ii)
#pragma unroll
      for (int jj = 0; jj < 8; ++jj)
        acc[ii][jj] += a[ii].x * bb[jj].x + a[ii].y * bb[jj].y +
                       a[ii].z * bb[jj].z + a[ii].w * bb[jj].w;
  }

  float* Sb = out + S_OFF + (size_t)bz * NN * NN;
#pragma unroll
  for (int ii = 0; ii < 8; ++ii) {
    int n = by * 128 + ty + 16 * ii;
    float4 f0 = make_float4(acc[ii][0], acc[ii][1], acc[ii][2], acc[ii][3]);
    float4 f1 = make_float4(acc[ii][4], acc[ii][5], acc[ii][6], acc[ii][7]);
    *(float4*)(Sb + (size_t)n * NN + bx * 128 + tx * 4) = f0;
    *(float4*)(Sb + (size_t)n * NN + bx * 128 + 64 + tx * 4) = f1;
  }

  // per-row partial {sum, sumsq} over this block's 128 cols; 16-lane shuffle reduce
#pragma unroll
  for (int ii = 0; ii < 8; ++ii) {
    float sp = 0.f, ssp = 0.f;
#pragma unroll
    for (int jj = 0; jj < 8; ++jj) {
      sp += acc[ii][jj];
      ssp = fmaf(acc[ii][jj], acc[ii][jj], ssp);
    }
#pragma unroll
    for (int off = 1; off < 16; off <<= 1) {   // stays within the 16-lane tx group
      sp  += __shfl_xor(sp, off, 64);
      ssp += __shfl_xor(ssp, off, 64);
    }
    if (tx == 0) {
      int n = by * 128 + ty + 16 * ii;
      size_t g = (size_t)bz * NN + n;
      float2 st = make_float2(sp, ssp);
      *(float2*)&ws[STAT_OFF + (g * 16 + bx) * 2] = st;
    }
  }
}

// ---------------- kernel 3: topk: loads-first + in-wave tau + prefix screen -> sort -> epilogue ----------------
__global__ __launch_bounds__(256) void topk_kernel(float* __restrict__ out,
                                                   float* __restrict__ ws) {
  __shared__ unsigned long long cand[4][CANDMAX];  // 3 KB only
  const int t = threadIdx.x;
  const int wv = t >> 6, lane = t & 63;
  const int g = blockIdx.x * 4 + wv;
  const int n = g & (NN - 1);

  // issue the 8 S-row loads FIRST, so the tau reduction hides their latency
  const float* row = out + S_OFF + (size_t)g * NN;
  float4 f0 = *(const float4*)(row + 0 * 256 + lane * 4);
  float4 f1 = *(const float4*)(row + 1 * 256 + lane * 4);
  float4 f2 = *(const float4*)(row + 2 * 256 + lane * 4);
  float4 f3 = *(const float4*)(row + 3 * 256 + lane * 4);
  float4 f4 = *(const float4*)(row + 4 * 256 + lane * 4);
  float4 f5 = *(const float4*)(row + 5 * 256 + lane * 4);
  float4 f6 = *(const float4*)(row + 6 * 256 + lane * 4);
  float4 f7 = *(const float4*)(row + 7 * 256 + lane * 4);

  // in-wave tau: reduce this row's 16 stat partials
  float sp = 0.f, ssp = 0.f;
  if (lane < 16) {
    float2 p = *(const float2*)&ws[STAT_OFF + ((size_t)g * 16 + lane) * 2];
    sp = p.x; ssp = p.y;
  }
#pragma unroll
  for (int off = 1; off < 64; off <<= 1) {
    sp  += __shfl_xor(sp, off, 64);
    ssp += __shfl_xor(ssp, off, 64);
  }
  const float mu = sp * (1.f / 2048.f);
  const float sigma = sqrtf(fmaxf(ssp * (1.f / 2048.f) - mu * mu, 1e-12f));
  const float tau = mu + 1.8627f * sigma;          // target ~64 candidates

  float v[32];
  *(float4*)&v[0]  = f0; *(float4*)&v[4]  = f1;
  *(float4*)&v[8]  = f2; *(float4*)&v[12] = f3;
  *(float4*)&v[16] = f4; *(float4*)&v[20] = f5;
  *(float4*)&v[24] = f6; *(float4*)&v[28] = f7;

  // ---- prefix screen (single shuffle-prefix; order-free, sort is total) ----
  unsigned pmask = 0u;
  int mycnt = 0;
#pragma unroll
  for (int jj = 0; jj < 32; ++jj) {
    int col = ((jj >> 2) << 8) + lane * 4 + (jj & 3);
    if (col != n && v[jj] > tau) { pmask |= 1u << jj; ++mycnt; }
  }
  int pre = mycnt;
#pragma unroll
  for (int off = 1; off < 64; off <<= 1) {
    int o = __shfl_up(pre, off, 64);
    if (lane >= off) pre += o;
  }
  const int base0 = pre - mycnt;                   // exclusive prefix
  const int c = __shfl(pre, 63, 64);               // wave-uniform total

  int* status = (int*)(ws + STATUS_OFF);
  if (c < TOPKK || c > CANDMAX) {                  // rare: defer to fallback kernel
    if (lane == 0) status[g] = 0;
    return;
  }
  if (lane == 0) status[g] = 1;

  {
    int pos = base0;
#pragma unroll
    for (int jj = 0; jj < 32; ++jj) {
      if ((pmask >> jj) & 1u) {
        int col = ((jj >> 2) << 8) + lane * 4 + (jj & 3);
        cand[wv][pos] = make_key(v[jj], col);
        ++pos;
      }
    }
  }
  __builtin_amdgcn_s_waitcnt(0);                   // LDS writes visible to own wave

  unsigned long long key;
  if (c <= 64) {
    key = (lane < c) ? cand[wv][lane] : 0ull;
    bitonic64_desc(key, lane);
  } else {
    key = cand[wv][lane];
    bitonic64_desc(key, lane);
    if (lane >= 32) { int idx = 64 + (lane - 32); key = (idx < c) ? cand[wv][idx] : 0ull; }
    bitonic64_desc(key, lane);
  }

  epilogue_write(out, key, g, lane);
}

// ---------------- kernel 4: fallback for rows with count outside [32,96] (expected ~1 row) ----------------
__global__ __launch_bounds__(256) void fb_kernel(float* __restrict__ out,
                                                 const float* __restrict__ ws) {
  __shared__ unsigned long long cand[4][64];
  const int t = threadIdx.x;
  const int wv = t >> 6, lane = t & 63;
  const int* status = (const int*)(ws + STATUS_OFF);

  for (int g = blockIdx.x * 4 + wv; g < (int)NROWS; g += 256 * 4) {
    if (status[g]) continue;
    const int n = g & (NN - 1);
    const float* row = out + S_OFF + (size_t)g * NN;
    float v[32];
#pragma unroll
    for (int jj = 0; jj < 8; ++jj) {
      float4 f = *(const float4*)(row + jj * 256 + lane * 4);
      v[jj * 4 + 0] = f.x; v[jj * 4 + 1] = f.y;
      v[jj * 4 + 2] = f.z; v[jj * 4 + 3] = f.w;
    }
    float s = 0.f, ss = 0.f;
#pragma unroll
    for (int jj = 0; jj < 32; ++jj) { s += v[jj]; ss = fmaf(v[jj], v[jj], ss); }
#pragma unroll
    for (int off = 1; off < 64; off <<= 1) {
      s += __shfl_xor(s, off, 64); ss += __shfl_xor(ss, off, 64);
    }
    const float mu = s * (1.f / 2048.f);
    const float sigma = sqrtf(fmaxf(ss * (1.f / 2048.f) - mu * mu, 1e-12f));
    {
      int d = n - lane * 4;
      if (d >= 0 && d < NN && (d & 255) < 4) v[((d >> 8) << 2) | (d & 3)] = NEG_INF;
    }
    float tau2 = mu + 2.0641f * sigma;
    float lo_b = -3.0e38f, hi_b = 3.0e38f;
    float step = sigma + 1e-20f;
    bool found = false;
    for (int it = 0; it < 40; ++it) {
      int cl = 0;
#pragma unroll
      for (int jj = 0; jj < 32; ++jj) cl += (v[jj] > tau2) ? 1 : 0;
#pragma unroll
      for (int off = 1; off < 64; off <<= 1) cl += __shfl_xor(cl, off, 64);
      if (cl >= TOPKK && cl <= 64) { found = true; break; }
      if (cl > 64) lo_b = fmaxf(lo_b, tau2); else hi_b = fminf(hi_b, tau2);
      float tn = 0.f; bool ok = false;
      if (it < 6) {
        float pp = fminf(fmaxf((float)cl, 1.f) * (1.f / 2048.f), 0.5f);
        float tt = sqrtf(-2.f * logf(pp));
        float zc = tt - (2.30753f + 0.27061f * tt) /
                        (1.f + tt * (0.99229f + 0.04481f * tt));
        zc = fmaxf(zc, 0.05f);
        tn = mu + 2.0641f * ((tau2 - mu) / zc);
        ok = (tn > lo_b && tn < hi_b);
      }
      if (!ok) {
        if (lo_b > -1.0e38f && hi_b < 1.0e38f) tn = 0.5f * lo_b + 0.5f * hi_b;
        else if (cl > 64) { tn = tau2 + step; step *= 2.f; }
        else              { tn = tau2 - step; step *= 2.f; }
      }
      tau2 = tn;
    }

    unsigned long long key = 0ull;
    if (found) {
      const unsigned long long below = (1ull << lane) - 1ull;
      int base = 0;
#pragma unroll
      for (int jj = 0; jj < 32; ++jj) {
        int col = ((jj >> 2) << 8) + lane * 4 + (jj & 3);
        bool pred = (v[jj] > tau2);
        unsigned long long mask = __ballot(pred);
        if (pred) cand[wv][base + __popcll(mask & below)] = make_key(v[jj], col);
        base += __popcll(mask);
      }
      __builtin_amdgcn_s_waitcnt(0);
      key = (lane < base) ? cand[wv][lane] : 0ull;
      bitonic64_desc(key, lane);
    } else {
      // exact serial extraction (measure-zero path)
      unsigned alive = 0xFFFFFFFFu;
      unsigned long long keysel = 0ull;
      for (int it = 0; it < TOPKK; ++it) {
        unsigned long long best = 0ull;
#pragma unroll
        for (int jj = 0; jj < 32; ++jj) {
          if ((alive >> jj) & 1u) {
            int col = ((jj >> 2) << 8) + lane * 4 + (jj & 3);
            unsigned long long kk = make_key(v[jj], col);
            if (kk > best) best = kk;
          }
        }
        unsigned long long b2 = best;
#pragma unroll
        for (int off = 1; off < 64; off <<= 1) {
          unsigned long long o = __shfl_xor(b2, off, 64);
          if (o > b2) b2 = o;
        }
        if (lane == it) keysel = b2;
        if (best == b2) {
#pragma unroll
          for (int jj = 0; jj < 32; ++jj) {
            int col = ((jj >> 2) << 8) + lane * 4 + (jj & 3);
            if (make_key(v[jj], col) == b2) alive &= ~(1u << jj);
          }
        }
      }
      key = keysel;
    }

    epilogue_write(out, key, g, lane);
  }
}

extern "C" void kernel_launch(void* const* d_in, const int* in_sizes, int n_in,
                              void* d_out, int out_size, void* d_ws, size_t ws_size,
                              hipStream_t stream) {
  const float* X  = (const float*)d_in[0];
  const float* W  = (const float*)d_in[1];
  const float* Bm = (const float*)d_in[2];
  float* out = (float*)d_out;
  float* ws  = (float*)d_ws;   // ~6.3 MB used

  hipLaunchKernelGGL(rt_kernel, dim3(512), dim3(256), 0, stream, X, W, Bm, out, ws);
  hipLaunchKernelGGL(s_stat_kernel, dim3(16, 16, 8), dim3(256), 0, stream, out, ws);
  hipLaunchKernelGGL(topk_kernel, dim3(4096), dim3(256), 0, stream, out, ws);
  hipLaunchKernelGGL(fb_kernel, dim3(256), dim3(256), 0, stream, out, ws);
}

// Round 21
// 133.364 us; speedup vs baseline: 1.1353x; 1.0001x over previous
//
#include <hip/hip_runtime.h>
#include <math.h>

#define BATCH 8
#define NN 2048
#define DIN 256
#define RANK 64
#define TOPKK 32
#define CANDMAX 96

typedef float v4f __attribute__((ext_vector_type(4)));

static constexpr size_t A_ELEMS = (size_t)BATCH * NN * NN;   // 33554432
static constexpr size_t S_OFF   = A_ELEMS;
static constexpr size_t R_OFF   = 2 * A_ELEMS;
static constexpr size_t NROWS   = (size_t)BATCH * NN;        // 16384

// ws layout (float offsets) — every word rewritten before read, every launch
static constexpr size_t T_OFF      = 0;                      // T[16384][64]
static constexpr size_t STAT_OFF   = 1048576;                // {sum,sumsq}[16384][16]
static constexpr size_t STATUS_OFF = STAT_OFF + NROWS * 32;  // int[16384]
// total ≈ 6.3 MB

#define NEG_INF (-__builtin_inff())

// ---------------- threefry2x32, JAX partitionable counter-mode (verified r3) ----------------
__device__ __forceinline__ unsigned rotl32(unsigned x, int d) {
  return (x << d) | (x >> (32 - d));
}

__device__ unsigned threefry_bits(unsigned flat) {
  const unsigned ks0 = 0u, ks1 = 42u, ks2 = 0u ^ 42u ^ 0x1BD11BDAu;
  unsigned x0 = 0u + ks0;
  unsigned x1 = flat + ks1;
#define TF_ROUND(r) { x0 += x1; x1 = rotl32(x1, r); x1 ^= x0; }
  TF_ROUND(13) TF_ROUND(15) TF_ROUND(26) TF_ROUND(6)
  x0 += ks1; x1 += ks2 + 1u;
  TF_ROUND(17) TF_ROUND(29) TF_ROUND(16) TF_ROUND(24)
  x0 += ks2; x1 += ks0 + 2u;
  TF_ROUND(13) TF_ROUND(15) TF_ROUND(26) TF_ROUND(6)
  x0 += ks0; x1 += ks1 + 3u;
  TF_ROUND(17) TF_ROUND(29) TF_ROUND(16) TF_ROUND(24)
  x0 += ks1; x1 += ks2 + 4u;
  TF_ROUND(13) TF_ROUND(15) TF_ROUND(26) TF_ROUND(6)
  x0 += ks2; x1 += ks0 + 5u;
#undef TF_ROUND
  return x0 ^ x1;
}

__device__ __forceinline__ unsigned long long make_key(float v, int col) {
  unsigned u = __float_as_uint(v);
  u = (u & 0x80000000u) ? ~u : (u | 0x80000000u);
  return ((unsigned long long)u << 32) | (unsigned)(~col);
}

__device__ __forceinline__ void decode_key(unsigned long long key, float& val, int& col) {
  unsigned hi = (unsigned)(key >> 32);
  unsigned ub = (hi & 0x80000000u) ? (hi ^ 0x80000000u) : ~hi;
  val = __uint_as_float(ub);
  col = (int)(~(unsigned)key) & (NN - 1);
}

// lane MUST be the within-wave lane id (threadIdx.x & 63) (r5 bug)
__device__ __forceinline__ void bitonic64_desc(unsigned long long& key, int lane) {
#pragma unroll
  for (int k = 2; k <= 64; k <<= 1) {
#pragma unroll
    for (int j = k >> 1; j >= 1; j >>= 1) {
      unsigned long long o = __shfl_xor(key, j, 64);
      bool lower = (lane & j) == 0;
      bool desc  = (lane & k) == 0;
      bool takeMax = (lower == desc);
      bool kgo = key > o;
      key = (takeMax == kgo) ? key : o;
    }
  }
}

// softmax + dropout + renorm + SCATTER-ONLY A write (A pre-zeroed by rt_kernel)
__device__ __forceinline__ void epilogue_write(float* __restrict__ out,
                                               unsigned long long key,
                                               int g, int lane) {
  float val; int col;
  decode_key(key, val, col);
  float m = __shfl(val, 0, 64);
  float e = (lane < TOPKK) ? expf(val - m) : 0.f;
  float s1 = e;
#pragma unroll
  for (int off = 1; off < 64; off <<= 1) s1 += __shfl_xor(s1, off, 64);
  float a1 = e / fmaxf(s1, 1e-6f);

  float a2 = 0.f;
  if (lane < TOPKK) {
    unsigned flat = (unsigned)g * 2048u + (unsigned)col;
    unsigned bits = threefry_bits(flat);
    float u = __uint_as_float((bits >> 9) | 0x3f800000u) - 1.0f;
    if (u <= 0.9f) a2 = a1 * (1.f / 0.9f);
  }
  float s2 = a2;
#pragma unroll
  for (int off = 1; off < 64; off <<= 1) s2 += __shfl_xor(s2, off, 64);
  float av = a2 / fmaxf(s2, 1e-6f);

  if (lane < TOPKK) out[(size_t)g * NN + col] = av;
}

// ---------------- kernel 1: R = X*W -> out; T = (R*B)/8 -> ws; + grid-stride A-zero (nt) ----------------
__global__ __launch_bounds__(256) void rt_kernel(const float* __restrict__ X,
                                                 const float* __restrict__ W,
                                                 const float* __restrict__ Bm,
                                                 float* __restrict__ out,
                                                 float* __restrict__ ws) {
  __shared__ float Xs[32][256];
  __shared__ float Bs[64][64];
  __shared__ float Rs[32][64];
  const int t = threadIdx.x;
  const int blk = blockIdx.x;
  const int b  = blk >> 6;
  const int rb = blk & 63;
  const float* Xb = X + ((size_t)b * NN + (size_t)rb * 32) * DIN;

#pragma unroll
  for (int it = 0; it < 8; ++it) {
    int flat = it * 1024 + t * 4;
    *(float4*)&Xs[flat >> 8][flat & 255] = *(const float4*)(Xb + flat);
  }
#pragma unroll
  for (int it = 0; it < 4; ++it) {
    int flat = it * 1024 + t * 4;
    *(float4*)&Bs[flat >> 6][flat & 63] = *(const float4*)(Bm + flat);
  }
  __syncthreads();

  const int j = t & 63, rg = t >> 6;
  float acc[8] = {0.f, 0.f, 0.f, 0.f, 0.f, 0.f, 0.f, 0.f};
  for (int k = 0; k < DIN; k += 4) {
    float w0 = W[(k + 0) * RANK + j];
    float w1 = W[(k + 1) * RANK + j];
    float w2 = W[(k + 2) * RANK + j];
    float w3 = W[(k + 3) * RANK + j];
#pragma unroll
    for (int ii = 0; ii < 8; ++ii) {
      float4 xv = *(const float4*)&Xs[rg * 8 + ii][k];
      acc[ii] += xv.x * w0 + xv.y * w1 + xv.z * w2 + xv.w * w3;
    }
  }
  const size_t grow0 = (size_t)b * NN + (size_t)rb * 32;
  float* Rout = out + R_OFF + grow0 * RANK;
#pragma unroll
  for (int ii = 0; ii < 8; ++ii) {
    Rout[(size_t)(rg * 8 + ii) * RANK + j] = acc[ii];
    Rs[rg * 8 + ii][j] = acc[ii];
  }
  __syncthreads();

  float acc2[8] = {0.f, 0.f, 0.f, 0.f, 0.f, 0.f, 0.f, 0.f};
  for (int r = 0; r < RANK; r += 4) {
    float b0 = Bs[r + 0][j];
    float b1 = Bs[r + 1][j];
    float b2 = Bs[r + 2][j];
    float b3 = Bs[r + 3][j];
#pragma unroll
    for (int ii = 0; ii < 8; ++ii) {
      float4 rv = *(const float4*)&Rs[rg * 8 + ii][r];
      acc2[ii] += rv.x * b0 + rv.y * b1 + rv.z * b2 + rv.w * b3;
    }
  }
  float* Tout = ws + T_OFF + grow0 * RANK;
#pragma unroll
  for (int ii = 0; ii < 8; ++ii)
    Tout[(size_t)(rg * 8 + ii) * RANK + j] = acc2[ii] * 0.125f;

  // grid-stride zero of the whole A region — NON-TEMPORAL so the zeros don't
  // evict S from L3 (S must stay resident for topk's re-read).
  {
    v4f* Az = (v4f*)out;
    v4f z = {0.f, 0.f, 0.f, 0.f};
    size_t base = (size_t)blk * 4096 + t;
#pragma unroll
    for (int i = 0; i < 16; ++i)
      __builtin_nontemporal_store(z, Az + base + (size_t)i * 256);
  }
}

// ---------------- kernel 2: S = T * R^T + stat partials; 8x8 thread tile (128x128 block) ----------------
__global__ __launch_bounds__(256) void s_stat_kernel(float* __restrict__ out,
                                                     float* __restrict__ ws) {
  __shared__ float Ts[128][68];  // row-major, padded (broadcast b128 reads), 34.8 KB
  __shared__ float Rs[128][64];  // per row c: unit u stored at (u ^ (c>>2))&15, 32.8 KB
  const int t = threadIdx.x;
  const int bx = blockIdx.x;  // col tile (128 cols)
  const int by = blockIdx.y;  // row tile (128 rows)
  const int bz = blockIdx.z;  // batch
  const float* Tg = ws + T_OFF + ((size_t)bz * NN + (size_t)by * 128) * RANK;
  const float* Rg = out + R_OFF + ((size_t)bz * NN + (size_t)bx * 128) * RANK;

#pragma unroll
  for (int it = 0; it < 8; ++it) {
    int flat = it * 1024 + t * 4;
    int r = flat >> 6, c = flat & 63;
    *(float4*)&Ts[r][c] = *(const float4*)(Tg + flat);
    int u_store = ((c >> 2) ^ (r >> 2)) & 15;
    *(float4*)&Rs[r][u_store * 4] = *(const float4*)(Rg + flat);
  }
  __syncthreads();

  const int tx = t & 15, ty = t >> 4;   // rows ty + 16*ii (ii<8); cols jh*64 + tx*4 + jq
  float acc[8][8];
#pragma unroll
  for (int ii = 0; ii < 8; ++ii)
#pragma unroll
    for (int jj = 0; jj < 8; ++jj) acc[ii][jj] = 0.f;

  for (int k = 0; k < 64; k += 4) {
    float4 a[8], bb[8];
#pragma unroll
    for (int ii = 0; ii < 8; ++ii) a[ii] = *(const float4*)&Ts[ty + 16 * ii][k];
#pragma unroll
    for (int jj = 0; jj < 8; ++jj) {
      int c = (jj >> 2) * 64 + tx * 4 + (jj & 3);   // (c>>2)&15 == tx for both halves
      bb[jj] = *(const float4*)&Rs[c][(((k >> 2) ^ tx) & 15) * 4];
    }
#pragma unroll
    for (int ii = 0; ii < 8; ++ii)
#pragma unroll
      for (int jj = 0; jj < 8; ++jj)
        acc[ii][jj] += a[ii].x * bb[jj].x + a[ii].y * bb[jj].y +
                       a[ii].z * bb[jj].z + a[ii].w * bb[jj].w;
  }

  float* Sb = out + S_OFF + (size_t)bz * NN * NN;
#pragma unroll
  for (int ii = 0; ii < 8; ++ii) {
    int n = by * 128 + ty + 16 * ii;
    float4 f0 = make_float4(acc[ii][0], acc[ii][1], acc[ii][2], acc[ii][3]);
    float4 f1 = make_float4(acc[ii][4], acc[ii][5], acc[ii][6], acc[ii][7]);
    *(float4*)(Sb + (size_t)n * NN + bx * 128 + tx * 4) = f0;
    *(float4*)(Sb + (size_t)n * NN + bx * 128 + 64 + tx * 4) = f1;
  }

  // per-row partial {sum, sumsq} over this block's 128 cols; 16-lane shuffle reduce
#pragma unroll
  for (int ii = 0; ii < 8; ++ii) {
    float sp = 0.f, ssp = 0.f;
#pragma unroll
    for (int jj = 0; jj < 8; ++jj) {
      sp += acc[ii][jj];
      ssp = fmaf(acc[ii][jj], acc[ii][jj], ssp);
    }
#pragma unroll
    for (int off = 1; off < 16; off <<= 1) {   // stays within the 16-lane tx group
      sp  += __shfl_xor(sp, off, 64);
      ssp += __shfl_xor(ssp, off, 64);
    }
    if (tx == 0) {
      int n = by * 128 + ty + 16 * ii;
      size_t g = (size_t)bz * NN + n;
      float2 st = make_float2(sp, ssp);
      *(float2*)&ws[STAT_OFF + (g * 16 + bx) * 2] = st;
    }
  }
}

// ---------------- kernel 3: topk: loads-first + in-wave tau + prefix screen -> sort -> epilogue ----------------
__global__ __launch_bounds__(256) void topk_kernel(float* __restrict__ out,
                                                   float* __restrict__ ws) {
  __shared__ unsigned long long cand[4][CANDMAX];  // 3 KB only
  const int t = threadIdx.x;
  const int wv = t >> 6, lane = t & 63;
  const int g = blockIdx.x * 4 + wv;
  const int n = g & (NN - 1);

  // issue the 8 S-row loads FIRST, so the tau reduction hides their latency
  const float* row = out + S_OFF + (size_t)g * NN;
  float4 f0 = *(const float4*)(row + 0 * 256 + lane * 4);
  float4 f1 = *(const float4*)(row + 1 * 256 + lane * 4);
  float4 f2 = *(const float4*)(row + 2 * 256 + lane * 4);
  float4 f3 = *(const float4*)(row + 3 * 256 + lane * 4);
  float4 f4 = *(const float4*)(row + 4 * 256 + lane * 4);
  float4 f5 = *(const float4*)(row + 5 * 256 + lane * 4);
  float4 f6 = *(const float4*)(row + 6 * 256 + lane * 4);
  float4 f7 = *(const float4*)(row + 7 * 256 + lane * 4);

  // in-wave tau: reduce this row's 16 stat partials
  float sp = 0.f, ssp = 0.f;
  if (lane < 16) {
    float2 p = *(const float2*)&ws[STAT_OFF + ((size_t)g * 16 + lane) * 2];
    sp = p.x; ssp = p.y;
  }
#pragma unroll
  for (int off = 1; off < 64; off <<= 1) {
    sp  += __shfl_xor(sp, off, 64);
    ssp += __shfl_xor(ssp, off, 64);
  }
  const float mu = sp * (1.f / 2048.f);
  const float sigma = sqrtf(fmaxf(ssp * (1.f / 2048.f) - mu * mu, 1e-12f));
  const float tau = mu + 1.8627f * sigma;          // target ~64 candidates

  float v[32];
  *(float4*)&v[0]  = f0; *(float4*)&v[4]  = f1;
  *(float4*)&v[8]  = f2; *(float4*)&v[12] = f3;
  *(float4*)&v[16] = f4; *(float4*)&v[20] = f5;
  *(float4*)&v[24] = f6; *(float4*)&v[28] = f7;

  // ---- prefix screen (single shuffle-prefix; order-free, sort is total) ----
  unsigned pmask = 0u;
  int mycnt = 0;
#pragma unroll
  for (int jj = 0; jj < 32; ++jj) {
    int col = ((jj >> 2) << 8) + lane * 4 + (jj & 3);
    if (col != n && v[jj] > tau) { pmask |= 1u << jj; ++mycnt; }
  }
  int pre = mycnt;
#pragma unroll
  for (int off = 1; off < 64; off <<= 1) {
    int o = __shfl_up(pre, off, 64);
    if (lane >= off) pre += o;
  }
  const int base0 = pre - mycnt;                   // exclusive prefix
  const int c = __shfl(pre, 63, 64);               // wave-uniform total

  int* status = (int*)(ws + STATUS_OFF);
  if (c < TOPKK || c > CANDMAX) {                  // rare: defer to fallback kernel
    if (lane == 0) status[g] = 0;
    return;
  }
  if (lane == 0) status[g] = 1;

  {
    int pos = base0;
#pragma unroll
    for (int jj = 0; jj < 32; ++jj) {
      if ((pmask >> jj) & 1u) {
        int col = ((jj >> 2) << 8) + lane * 4 + (jj & 3);
        cand[wv][pos] = make_key(v[jj], col);
        ++pos;
      }
    }
  }
  __builtin_amdgcn_s_waitcnt(0);                   // LDS writes visible to own wave

  unsigned long long key;
  if (c <= 64) {
    key = (lane < c) ? cand[wv][lane] : 0ull;
    bitonic64_desc(key, lane);
  } else {
    key = cand[wv][lane];
    bitonic64_desc(key, lane);
    if (lane >= 32) { int idx = 64 + (lane - 32); key = (idx < c) ? cand[wv][idx] : 0ull; }
    bitonic64_desc(key, lane);
  }

  epilogue_write(out, key, g, lane);
}

// ---------------- kernel 4: fallback for rows with count outside [32,96] (expected ~1 row) ----------------
__global__ __launch_bounds__(256) void fb_kernel(float* __restrict__ out,
                                                 const float* __restrict__ ws) {
  __shared__ unsigned long long cand[4][64];
  const int t = threadIdx.x;
  const int wv = t >> 6, lane = t & 63;
  const int* status = (const int*)(ws + STATUS_OFF);

  for (int g = blockIdx.x * 4 + wv; g < (int)NROWS; g += 256 * 4) {
    if (status[g]) continue;
    const int n = g & (NN - 1);
    const float* row = out + S_OFF + (size_t)g * NN;
    float v[32];
#pragma unroll
    for (int jj = 0; jj < 8; ++jj) {
      float4 f = *(const float4*)(row + jj * 256 + lane * 4);
      v[jj * 4 + 0] = f.x; v[jj * 4 + 1] = f.y;
      v[jj * 4 + 2] = f.z; v[jj * 4 + 3] = f.w;
    }
    float s = 0.f, ss = 0.f;
#pragma unroll
    for (int jj = 0; jj < 32; ++jj) { s += v[jj]; ss = fmaf(v[jj], v[jj], ss); }
#pragma unroll
    for (int off = 1; off < 64; off <<= 1) {
      s += __shfl_xor(s, off, 64); ss += __shfl_xor(ss, off, 64);
    }
    const float mu = s * (1.f / 2048.f);
    const float sigma = sqrtf(fmaxf(ss * (1.f / 2048.f) - mu * mu, 1e-12f));
    {
      int d = n - lane * 4;
      if (d >= 0 && d < NN && (d & 255) < 4) v[((d >> 8) << 2) | (d & 3)] = NEG_INF;
    }
    float tau2 = mu + 2.0641f * sigma;
    float lo_b = -3.0e38f, hi_b = 3.0e38f;
    float step = sigma + 1e-20f;
    bool found = false;
    for (int it = 0; it < 40; ++it) {
      int cl = 0;
#pragma unroll
      for (int jj = 0; jj < 32; ++jj) cl += (v[jj] > tau2) ? 1 : 0;
#pragma unroll
      for (int off = 1; off < 64; off <<= 1) cl += __shfl_xor(cl, off, 64);
      if (cl >= TOPKK && cl <= 64) { found = true; break; }
      if (cl > 64) lo_b = fmaxf(lo_b, tau2); else hi_b = fminf(hi_b, tau2);
      float tn = 0.f; bool ok = false;
      if (it < 6) {
        float pp = fminf(fmaxf((float)cl, 1.f) * (1.f / 2048.f), 0.5f);
        float tt = sqrtf(-2.f * logf(pp));
        float zc = tt - (2.30753f + 0.27061f * tt) /
                        (1.f + tt * (0.99229f + 0.04481f * tt));
        zc = fmaxf(zc, 0.05f);
        tn = mu + 2.0641f * ((tau2 - mu) / zc);
        ok = (tn > lo_b && tn < hi_b);
      }
      if (!ok) {
        if (lo_b > -1.0e38f && hi_b < 1.0e38f) tn = 0.5f * lo_b + 0.5f * hi_b;
        else if (cl > 64) { tn = tau2 + step; step *= 2.f; }
        else              { tn = tau2 - step; step *= 2.f; }
      }
      tau2 = tn;
    }

    unsigned long long key = 0ull;
    if (found) {
      const unsigned long long below = (1ull << lane) - 1ull;
      int base = 0;
#pragma unroll
      for (int jj = 0; jj < 32; ++jj) {
        int col = ((jj >> 2) << 8) + lane * 4 + (jj & 3);
        bool pred = (v[jj] > tau2);
        unsigned long long mask = __ballot(pred);
        if (pred) cand[wv][base + __popcll(mask & below)] = make_key(v[jj], col);
        base += __popcll(mask);
      }
      __builtin_amdgcn_s_waitcnt(0);
      key = (lane < base) ? cand[wv][lane] : 0ull;
      bitonic64_desc(key, lane);
    } else {
      // exact serial extraction (measure-zero path)
      unsigned alive = 0xFFFFFFFFu;
      unsigned long long keysel = 0ull;
      for (int it = 0; it < TOPKK; ++it) {
        unsigned long long best = 0ull;
#pragma unroll
        for (int jj = 0; jj < 32; ++jj) {
          if ((alive >> jj) & 1u) {
            int col = ((jj >> 2) << 8) + lane * 4 + (jj & 3);
            unsigned long long kk = make_key(v[jj], col);
            if (kk > best) best = kk;
          }
        }
        unsigned long long b2 = best;
#pragma unroll
        for (int off = 1; off < 64; off <<= 1) {
          unsigned long long o = __shfl_xor(b2, off, 64);
          if (o > b2) b2 = o;
        }
        if (lane == it) keysel = b2;
        if (best == b2) {
#pragma unroll
          for (int jj = 0; jj < 32; ++jj) {
            int col = ((jj >> 2) << 8) + lane * 4 + (jj & 3);
            if (make_key(v[jj], col) == b2) alive &= ~(1u << jj);
          }
        }
      }
      key = keysel;
    }

    epilogue_write(out, key, g, lane);
  }
}

extern "C" void kernel_launch(void* const* d_in, const int* in_sizes, int n_in,
                              void* d_out, int out_size, void* d_ws, size_t ws_size,
                              hipStream_t stream) {
  const float* X  = (const float*)d_in[0];
  const float* W  = (const float*)d_in[1];
  const float* Bm = (const float*)d_in[2];
  float* out = (float*)d_out;
  float* ws  = (float*)d_ws;   // ~6.3 MB used

  hipLaunchKernelGGL(rt_kernel, dim3(512), dim3(256), 0, stream, X, W, Bm, out, ws);
  hipLaunchKernelGGL(s_stat_kernel, dim3(16, 16, 8), dim3(256), 0, stream, out, ws);
  hipLaunchKernelGGL(topk_kernel, dim3(4096), dim3(256), 0, stream, out, ws);
  hipLaunchKernelGGL(fb_kernel, dim3(256), dim3(256), 0, stream, out, ws);
}